// Round 1
// baseline (2718.741 us; speedup 1.0000x reference)
//
#include <hip/hip_runtime.h>
#include <hip/hip_bf16.h>

typedef __attribute__((ext_vector_type(8))) short short8;
typedef __attribute__((ext_vector_type(4))) float f32x4;
typedef unsigned short ushort;

#define GBLK 64   // persistent scan blocks (<=256 CUs -> all co-resident)

__device__ inline ushort f2bf(float x) {
  __hip_bfloat16 h = __float2bfloat16(x);
  return *reinterpret_cast<ushort*>(&h);
}

// ---------------- cast f32 -> bf16 ----------------
__global__ void cast_kernel(const float* __restrict__ in, ushort* __restrict__ out, int n) {
  int i = blockIdx.x * blockDim.x + threadIdx.x;
  int stride = gridDim.x * blockDim.x;
  for (; i < n; i += stride) out[i] = f2bf(in[i]);
}

// ---------------- residual MLP: ln(relu(W2 relu(W1 x)) + relu(W1 x)) ----------------
// 16 rows per block, 256 threads. fp32 (exact-ish; small: 1024x256x256 x2)
__global__ __launch_bounds__(256) void mlp_kernel(
    const float* __restrict__ X,
    const float* __restrict__ W1, const float* __restrict__ b1,
    const float* __restrict__ W2, const float* __restrict__ b2,
    const float* __restrict__ g, const float* __restrict__ beta,
    float* __restrict__ out_f32, ushort* __restrict__ out_bf16)
{
  __shared__ float Xs[16 * 260];   // X tile, later reused as H2 tile
  __shared__ float H1s[16 * 260];
  __shared__ float mu_s[16], rs_s[16];
  int tid = threadIdx.x;
  int r0 = blockIdx.x * 16;
  for (int q = 0; q < 16; ++q) Xs[q * 260 + tid] = X[(r0 + q) * 256 + tid];
  __syncthreads();
  int r = tid & 15, jg = tid >> 4;
  // layer 1
  for (int jj = 0; jj < 16; ++jj) {
    int j = jg * 16 + jj;  // quad-uniform -> broadcast W loads
    const float4* wrow = (const float4*)(W1 + j * 256);
    const float4* xrow = (const float4*)(Xs + r * 260);
    float acc = 0.f;
#pragma unroll 8
    for (int kq = 0; kq < 64; ++kq) {
      float4 w = wrow[kq], x = xrow[kq];
      acc += w.x * x.x + w.y * x.y + w.z * x.z + w.w * x.w;
    }
    acc += b1[j];
    H1s[r * 260 + j] = acc > 0.f ? acc : 0.f;
  }
  __syncthreads();
  // layer 2 + residual
  for (int jj = 0; jj < 16; ++jj) {
    int j = jg * 16 + jj;
    const float4* wrow = (const float4*)(W2 + j * 256);
    const float4* hrow = (const float4*)(H1s + r * 260);
    float acc = 0.f;
#pragma unroll 8
    for (int kq = 0; kq < 64; ++kq) {
      float4 w = wrow[kq], x = hrow[kq];
      acc += w.x * x.x + w.y * x.y + w.z * x.z + w.w * x.w;
    }
    acc += b2[j];
    float v = (acc > 0.f ? acc : 0.f) + H1s[r * 260 + j];
    Xs[r * 260 + j] = v;   // H2
  }
  __syncthreads();
  if (tid < 16) {
    float s = 0.f, s2 = 0.f;
    for (int k = 0; k < 256; ++k) { float x = Xs[tid * 260 + k]; s += x; s2 += x * x; }
    float mu = s * (1.0f / 256.0f);
    float var = s2 * (1.0f / 256.0f) - mu * mu;
    mu_s[tid] = mu; rs_s[tid] = rsqrtf(var + 1e-5f);
  }
  __syncthreads();
  for (int q = 0; q < 16; ++q) {
    float x = (Xs[q * 260 + tid] - mu_s[q]) * rs_s[q] * g[tid] + beta[tid];
    out_f32[(r0 + q) * 256 + tid] = x;
    if (out_bf16) out_bf16[(r0 + q) * 256 + tid] = f2bf(x);
  }
}

// ---------------- start head: logits (K=256) + log_softmax over 1024 ----------------
__global__ __launch_bounds__(1024) void shead_kernel(
    const float* __restrict__ h, const float* __restrict__ Wo, const float* __restrict__ bo,
    float* __restrict__ start)
{
  __shared__ float red[16];
  __shared__ float lse_s;
  int tid = threadIdx.x;
  const float4* wr = (const float4*)Wo;
  const float4* hr = (const float4*)(h + tid * 256);
  float acc = 0.f;
  for (int kq = 0; kq < 64; ++kq) {
    float4 w = wr[kq], x = hr[kq];
    acc += w.x * x.x + w.y * x.y + w.z * x.z + w.w * x.w;
  }
  acc += bo[0];
  // logits ~ N(0,1): no-max lse is safe
  float s = __expf(acc);
  for (int m = 1; m < 64; m <<= 1) s += __shfl_xor(s, m);
  if ((tid & 63) == 0) red[tid >> 6] = s;
  __syncthreads();
  if (tid == 0) {
    float t = 0.f;
    for (int w = 0; w < 16; ++w) t += red[w];
    lse_s = logf(t);
  }
  __syncthreads();
  start[tid] = acc - lse_s;
}

// ---------------- bf16 MFMA GEMM, tile 64(M) x 32(N), K=256, D = A @ B^T ----------------
// mode 0: store D + bias  (transition logits)
// mode 1: esum[row] += sum_cols exp(D + bias[col])   (emission row-sumexp, col-masked)
// mode 2: B-rows gathered via text; store transposed: out[tb*1024+row] = D + bias[v] - log(esum[row])
__global__ __launch_bounds__(256) void gemm_kernel(
    const ushort* __restrict__ A, const ushort* __restrict__ Bw,
    int mode, int Nvalid,
    const float* __restrict__ bias,
    float* __restrict__ out, float* __restrict__ esum, const int* __restrict__ text)
{
  __shared__ ushort As[64 * 264];
  __shared__ ushort Bs[32 * 264];
  int tid = threadIdx.x;
  int m0 = blockIdx.x * 64, n0 = blockIdx.y * 32;
#pragma unroll
  for (int q = 0; q < 8; ++q) {
    int idx = q * 256 + tid;
    int row = idx >> 5, c8 = idx & 31;
    *(short8*)(As + row * 264 + c8 * 8) = *(const short8*)(A + (m0 + row) * 256 + c8 * 8);
  }
#pragma unroll
  for (int q = 0; q < 4; ++q) {
    int idx = q * 256 + tid;
    int row = idx >> 5, c8 = idx & 31;
    int grow = n0 + row;
    short8 val = {0, 0, 0, 0, 0, 0, 0, 0};
    if (mode == 2) {
      int v = text[(grow & 15) * 256 + (grow >> 4)];
      val = *(const short8*)(Bw + v * 256 + c8 * 8);
    } else if (grow < Nvalid) {
      val = *(const short8*)(Bw + grow * 256 + c8 * 8);
    }
    *(short8*)(Bs + row * 264 + c8 * 8) = val;
  }
  __syncthreads();
  int lane = tid & 63, wave = tid >> 6;
  int r16 = lane & 15, quad = lane >> 4;
  f32x4 acc0 = {0.f, 0.f, 0.f, 0.f}, acc1 = {0.f, 0.f, 0.f, 0.f};
#pragma unroll
  for (int kb = 0; kb < 8; ++kb) {
    short8 a  = *(const short8*)(As + (wave * 16 + r16) * 264 + kb * 32 + quad * 8);
    short8 b0 = *(const short8*)(Bs + r16 * 264 + kb * 32 + quad * 8);
    short8 b1 = *(const short8*)(Bs + (16 + r16) * 264 + kb * 32 + quad * 8);
    acc0 = __builtin_amdgcn_mfma_f32_16x16x32_bf16(a, b0, acc0, 0, 0, 0);
    acc1 = __builtin_amdgcn_mfma_f32_16x16x32_bf16(a, b1, acc1, 0, 0, 0);
  }
  if (mode == 0) {
#pragma unroll
    for (int rr = 0; rr < 4; ++rr) {
      int row = m0 + wave * 16 + quad * 4 + rr;
      int c0 = n0 + r16, c1 = n0 + 16 + r16;
      out[row * 1024 + c0] = acc0[rr] + bias[c0];
      out[row * 1024 + c1] = acc1[rr] + bias[c1];
    }
  } else if (mode == 1) {
    float sums[4];
#pragma unroll
    for (int rr = 0; rr < 4; ++rr) {
      int c0 = n0 + r16, c1 = n0 + 16 + r16;
      float p0 = (c0 < Nvalid) ? __expf(acc0[rr] + bias[c0]) : 0.f;
      float p1 = (c1 < Nvalid) ? __expf(acc1[rr] + bias[c1]) : 0.f;
      float s = p0 + p1;
      s += __shfl_xor(s, 1); s += __shfl_xor(s, 2);
      s += __shfl_xor(s, 4); s += __shfl_xor(s, 8);
      sums[rr] = s;
    }
    if (r16 == 0) {
#pragma unroll
      for (int rr = 0; rr < 4; ++rr)
        atomicAdd(esum + m0 + wave * 16 + quad * 4 + rr, sums[rr]);
    }
  } else {
    int c0 = m0 + wave * 16 + quad * 4;  // 4 consecutive state rows
    int tb0 = n0 + r16, tb1 = n0 + 16 + r16;
    int v0 = text[(tb0 & 15) * 256 + (tb0 >> 4)];
    int v1 = text[(tb1 & 15) * 256 + (tb1 >> 4)];
    float l0 = logf(esum[c0]), l1 = logf(esum[c0 + 1]);
    float l2 = logf(esum[c0 + 2]), l3 = logf(esum[c0 + 3]);
    float4 o0, o1;
    o0.x = acc0[0] + bias[v0] - l0; o0.y = acc0[1] + bias[v0] - l1;
    o0.z = acc0[2] + bias[v0] - l2; o0.w = acc0[3] + bias[v0] - l3;
    o1.x = acc1[0] + bias[v1] - l0; o1.y = acc1[1] + bias[v1] - l1;
    o1.z = acc1[2] + bias[v1] - l2; o1.w = acc1[3] + bias[v1] - l3;
    *(float4*)(out + tb0 * 1024 + c0) = o0;
    *(float4*)(out + tb1 * 1024 + c0) = o1;
  }
}

// ---------------- transition: per-row log_softmax, scatter exp(T) in B-fragment order ----------------
// frag element (i,j) -> texp_frag[(((j>>4)*32 + (i>>5))*64 + ((i>>3)&3)*16 + (j&15))*8 + (i&7)]
__global__ __launch_bounds__(256) void trans_kernel(
    const float* __restrict__ logits, ushort* __restrict__ texp_frag)
{
  __shared__ float red[4];
  __shared__ float lse_s;
  int i = blockIdx.x, tid = threadIdx.x;
  float x[4];
  float s = 0.f;
#pragma unroll
  for (int q = 0; q < 4; ++q) { x[q] = logits[i * 1024 + q * 256 + tid]; s += __expf(x[q]); }
  for (int m = 1; m < 64; m <<= 1) s += __shfl_xor(s, m);
  if ((tid & 63) == 0) red[tid >> 6] = s;
  __syncthreads();
  if (tid == 0) lse_s = logf(red[0] + red[1] + red[2] + red[3]);
  __syncthreads();
  float lse = lse_s;
  int kblk = i >> 5, quad = (i >> 3) & 3, idx = i & 7;
#pragma unroll
  for (int q = 0; q < 4; ++q) {
    int j = q * 256 + tid;
    int pos = (((j >> 4) * 32 + kblk) * 64 + quad * 16 + (j & 15)) * 8 + idx;
    texp_frag[pos] = f2bf(__expf(x[q] - lse));
  }
}

// ---------------- alpha0 = start + emit[t=0] ----------------
__global__ void alpha0_kernel(const float* __restrict__ start, const float* __restrict__ emitg,
                              float* __restrict__ alpha)
{
  int i = blockIdx.x * 256 + threadIdx.x;  // grid 64x256 = 16384
  alpha[i] = start[i & 1023] + emitg[i];
}

// ---------------- persistent forward scan: 255 steps, custom grid barrier ----------------
// block p owns columns [16p, 16p+16). alpha double-buffered by t parity.
__global__ __launch_bounds__(256, 1) void scan_kernel(
    const ushort* __restrict__ texp_frag,
    const float* __restrict__ emitg,
    float* __restrict__ alpha,          // [2][16*1024]
    unsigned int* __restrict__ cnt)     // [256], zeroed
{
  __shared__ ushort aexp[16 * 1032];    // bf16, padded rows (2-way-conflict-free b128)
  __shared__ float redw[4][16];
  __shared__ float mrow[16];
  __shared__ float ksum[3 * 256];
  int tid = threadIdx.x;
  int lane = tid & 63, wave = tid >> 6;
  int r16 = lane & 15, quad = lane >> 4;
  int p = blockIdx.x;

  for (int t = 1; t < 256; ++t) {
    if (tid == 0 && t > 1) {
      while (__hip_atomic_load(cnt + (t - 1), __ATOMIC_RELAXED, __HIP_MEMORY_SCOPE_AGENT) < (unsigned)GBLK)
        __builtin_amdgcn_s_sleep(2);
      __threadfence();   // acquire: invalidate L1/L2 so alpha reads are fresh
    }
    __syncthreads();

    // read alpha[t-1] (64KB, L2-shared per XCD), per-row max (exact, replicated)
    const float4* ap = (const float4*)(alpha + ((t - 1) & 1) * 16384);
    float4 v[16];
    float rm[16];
#pragma unroll
    for (int q = 0; q < 16; ++q) {
      v[q] = ap[q * 256 + tid];                       // float4 q lies entirely in row q
      rm[q] = fmaxf(fmaxf(v[q].x, v[q].y), fmaxf(v[q].z, v[q].w));
    }
#pragma unroll
    for (int q = 0; q < 16; ++q)
      for (int m = 1; m < 64; m <<= 1) rm[q] = fmaxf(rm[q], __shfl_xor(rm[q], m));
    if (lane == 0) {
#pragma unroll
      for (int q = 0; q < 16; ++q) redw[wave][q] = rm[q];
    }
    __syncthreads();
    float m16[16];
#pragma unroll
    for (int q = 0; q < 16; ++q)
      m16[q] = fmaxf(fmaxf(redw[0][q], redw[1][q]), fmaxf(redw[2][q], redw[3][q]));
    if (tid < 16)
      mrow[tid] = fmaxf(fmaxf(redw[0][tid], redw[1][tid]), fmaxf(redw[2][tid], redw[3][tid]));
    // exp + pack to LDS A-fragments
#pragma unroll
    for (int q = 0; q < 16; ++q) {
      ushort4 u;
      u.x = f2bf(__expf(v[q].x - m16[q]));
      u.y = f2bf(__expf(v[q].y - m16[q]));
      u.z = f2bf(__expf(v[q].z - m16[q]));
      u.w = f2bf(__expf(v[q].w - m16[q]));
      *(ushort4*)(aexp + q * 1032 + 4 * tid) = u;
    }
    __syncthreads();

    // 4-wave split-K MFMA: D[b][j] = sum_i aexp[b][i] * Texp[i][j]
    f32x4 acc = {0.f, 0.f, 0.f, 0.f};
    const short8* tf = (const short8*)texp_frag;
#pragma unroll
    for (int it = 0; it < 8; ++it) {
      int k = wave * 8 + it;   // k-block of 32
      short8 a = *(const short8*)(aexp + r16 * 1032 + k * 32 + quad * 8);
      short8 b = tf[(p * 32 + k) * 64 + lane];
      acc = __builtin_amdgcn_mfma_f32_16x16x32_bf16(a, b, acc, 0, 0, 0);
    }
    if (wave != 0) *(f32x4*)(ksum + (wave - 1) * 256 + lane * 4) = acc;
    __syncthreads();
    if (wave == 0) {
      f32x4 s1 = *(const f32x4*)(ksum + 0 * 256 + lane * 4);
      f32x4 s2 = *(const f32x4*)(ksum + 1 * 256 + lane * 4);
      f32x4 s3 = *(const f32x4*)(ksum + 2 * 256 + lane * 4);
      acc = acc + s1 + s2 + s3;
      int jg = p * 16 + r16;
      float* aout = alpha + (t & 1) * 16384;
#pragma unroll
      for (int rr = 0; rr < 4; ++rr) {
        int b = quad * 4 + rr;
        float val = mrow[b] + logf(acc[rr]) + emitg[(t * 16 + b) * 1024 + jg];
        aout[b * 1024 + jg] = val;
      }
    }
    __syncthreads();
    if (tid == 0) {
      __threadfence();  // release: write back L2 so other XCDs see alpha slice
      __hip_atomic_fetch_add(cnt + t, 1u, __ATOMIC_RELAXED, __HIP_MEMORY_SCOPE_AGENT);
    }
  }
}

// ---------------- final: sum_b logsumexp_j(alpha_N[b,j]) ----------------
__global__ __launch_bounds__(256) void final_kernel(const float* __restrict__ alphaN,
                                                    float* __restrict__ out)
{
  __shared__ float red[4];
  int tid = threadIdx.x, lane = tid & 63, wave = tid >> 6;
  float total = 0.f;
  for (int b = 0; b < 16; ++b) {
    float4 v = ((const float4*)(alphaN + b * 1024))[tid];
    float mx = fmaxf(fmaxf(v.x, v.y), fmaxf(v.z, v.w));
    for (int m = 1; m < 64; m <<= 1) mx = fmaxf(mx, __shfl_xor(mx, m));
    if (lane == 0) red[wave] = mx;
    __syncthreads();
    mx = fmaxf(fmaxf(red[0], red[1]), fmaxf(red[2], red[3]));
    __syncthreads();
    float s = __expf(v.x - mx) + __expf(v.y - mx) + __expf(v.z - mx) + __expf(v.w - mx);
    for (int m = 1; m < 64; m <<= 1) s += __shfl_xor(s, m);
    if (lane == 0) red[wave] = s;
    __syncthreads();
    s = red[0] + red[1] + red[2] + red[3];
    total += mx + logf(s);
    __syncthreads();
  }
  if (tid == 0) out[0] = total;
}

extern "C" void kernel_launch(void* const* d_in, const int* in_sizes, int n_in,
                              void* d_out, int out_size, void* d_ws, size_t ws_size,
                              hipStream_t stream)
{
  (void)in_sizes; (void)n_in; (void)out_size; (void)ws_size;
  const float* start_emb = (const float*)d_in[0];
  const float* state_emb = (const float*)d_in[1];
  const float* pre_emb   = (const float*)d_in[2];
  const float* s_W1 = (const float*)d_in[3];  const float* s_b1 = (const float*)d_in[4];
  const float* s_W2 = (const float*)d_in[5];  const float* s_b2 = (const float*)d_in[6];
  const float* s_g  = (const float*)d_in[7];  const float* s_be = (const float*)d_in[8];
  const float* s_Wo = (const float*)d_in[9];  const float* s_bo = (const float*)d_in[10];
  const float* t_W1 = (const float*)d_in[11]; const float* t_b1 = (const float*)d_in[12];
  const float* t_W2 = (const float*)d_in[13]; const float* t_b2 = (const float*)d_in[14];
  const float* t_g  = (const float*)d_in[15]; const float* t_be = (const float*)d_in[16];
  const float* t_Wo = (const float*)d_in[17]; const float* t_bo = (const float*)d_in[18];
  const float* e_W1 = (const float*)d_in[19]; const float* e_b1 = (const float*)d_in[20];
  const float* e_W2 = (const float*)d_in[21]; const float* e_b2 = (const float*)d_in[22];
  const float* e_g  = (const float*)d_in[23]; const float* e_be = (const float*)d_in[24];
  const float* e_Wo = (const float*)d_in[25]; const float* e_bo = (const float*)d_in[26];
  const int*   text = (const int*)d_in[27];
  float* out = (float*)d_out;

  char* ws = (char*)d_ws;
  size_t off = 0;
  auto alloc = [&](size_t bytes) -> char* {
    char* p = ws + off;
    off = (off + bytes + 255) & ~(size_t)255;
    return p;
  };
  unsigned int* cnt = (unsigned int*)alloc(256 * 4);       // @0, 1024B
  float* esum       = (float*)alloc(1024 * 4);             // @1024, contiguous with cnt
  float* start_v    = (float*)alloc(1024 * 4);
  float* alpha      = (float*)alloc(2 * 16 * 1024 * 4);
  float* h_s        = (float*)alloc(1024 * 256 * 4);
  float* h_t        = (float*)alloc(1024 * 256 * 4);
  float* h_e        = (float*)alloc(1024 * 256 * 4);
  ushort* h_t_bf    = (ushort*)alloc(1024 * 256 * 2);
  ushort* h_e_bf    = (ushort*)alloc(1024 * 256 * 2);
  ushort* tWo_bf    = (ushort*)alloc(1024 * 256 * 2);
  ushort* eWo_bf    = (ushort*)alloc(10000 * 256 * 2);
  float* tlogits    = (float*)alloc(1024 * 1024 * 4);
  ushort* texp_frag = (ushort*)alloc(1024 * 1024 * 2);
  float* emitg      = (float*)alloc(4096 * 1024 * 4);

  hipMemsetAsync(ws, 0, 5120, stream);  // cnt + esum

  cast_kernel<<<256, 256, 0, stream>>>(t_Wo, tWo_bf, 1024 * 256);
  cast_kernel<<<512, 256, 0, stream>>>(e_Wo, eWo_bf, 10000 * 256);

  mlp_kernel<<<64, 256, 0, stream>>>(start_emb, s_W1, s_b1, s_W2, s_b2, s_g, s_be, h_s, nullptr);
  mlp_kernel<<<64, 256, 0, stream>>>(state_emb, t_W1, t_b1, t_W2, t_b2, t_g, t_be, h_t, h_t_bf);
  mlp_kernel<<<64, 256, 0, stream>>>(pre_emb,  e_W1, e_b1, e_W2, e_b2, e_g, e_be, h_e, h_e_bf);

  shead_kernel<<<1, 1024, 0, stream>>>(h_s, s_Wo, s_bo, start_v);

  gemm_kernel<<<dim3(16, 32),  256, 0, stream>>>(h_t_bf, tWo_bf, 0, 1024,  t_bo, tlogits, nullptr, nullptr);
  trans_kernel<<<1024, 256, 0, stream>>>(tlogits, texp_frag);
  gemm_kernel<<<dim3(16, 313), 256, 0, stream>>>(h_e_bf, eWo_bf, 1, 10000, e_bo, nullptr, esum, nullptr);
  gemm_kernel<<<dim3(16, 128), 256, 0, stream>>>(h_e_bf, eWo_bf, 2, 4096,  e_bo, emitg, esum, text);

  alpha0_kernel<<<64, 256, 0, stream>>>(start_v, emitg, alpha);
  scan_kernel<<<GBLK, 256, 0, stream>>>(texp_frag, emitg, alpha, cnt);
  final_kernel<<<1, 256, 0, stream>>>(alpha + 16384, out);
}

// Round 2
// 2659.478 us; speedup vs baseline: 1.0223x; 1.0223x over previous
//
#include <hip/hip_runtime.h>
#include <hip/hip_bf16.h>

typedef __attribute__((ext_vector_type(8))) short short8;
typedef __attribute__((ext_vector_type(4))) float f32x4;
typedef unsigned short ushort;
typedef unsigned long long u64;

#define GBLK 64   // persistent scan blocks (<=256 CUs -> all co-resident)

__device__ inline ushort f2bf(float x) {
  __hip_bfloat16 h = __float2bfloat16(x);
  return *reinterpret_cast<ushort*>(&h);
}

// ---------------- cast f32 -> bf16 ----------------
__global__ void cast_kernel(const float* __restrict__ in, ushort* __restrict__ out, int n) {
  int i = blockIdx.x * blockDim.x + threadIdx.x;
  int stride = gridDim.x * blockDim.x;
  for (; i < n; i += stride) out[i] = f2bf(in[i]);
}

// ---------------- residual MLP: ln(relu(W2 relu(W1 x)) + relu(W1 x)) ----------------
__global__ __launch_bounds__(256) void mlp_kernel(
    const float* __restrict__ X,
    const float* __restrict__ W1, const float* __restrict__ b1,
    const float* __restrict__ W2, const float* __restrict__ b2,
    const float* __restrict__ g, const float* __restrict__ beta,
    float* __restrict__ out_f32, ushort* __restrict__ out_bf16)
{
  __shared__ float Xs[16 * 260];
  __shared__ float H1s[16 * 260];
  __shared__ float mu_s[16], rs_s[16];
  int tid = threadIdx.x;
  int r0 = blockIdx.x * 16;
  for (int q = 0; q < 16; ++q) Xs[q * 260 + tid] = X[(r0 + q) * 256 + tid];
  __syncthreads();
  int r = tid & 15, jg = tid >> 4;
  for (int jj = 0; jj < 16; ++jj) {
    int j = jg * 16 + jj;
    const float4* wrow = (const float4*)(W1 + j * 256);
    const float4* xrow = (const float4*)(Xs + r * 260);
    float acc = 0.f;
#pragma unroll 8
    for (int kq = 0; kq < 64; ++kq) {
      float4 w = wrow[kq], x = xrow[kq];
      acc += w.x * x.x + w.y * x.y + w.z * x.z + w.w * x.w;
    }
    acc += b1[j];
    H1s[r * 260 + j] = acc > 0.f ? acc : 0.f;
  }
  __syncthreads();
  for (int jj = 0; jj < 16; ++jj) {
    int j = jg * 16 + jj;
    const float4* wrow = (const float4*)(W2 + j * 256);
    const float4* hrow = (const float4*)(H1s + r * 260);
    float acc = 0.f;
#pragma unroll 8
    for (int kq = 0; kq < 64; ++kq) {
      float4 w = wrow[kq], x = hrow[kq];
      acc += w.x * x.x + w.y * x.y + w.z * x.z + w.w * x.w;
    }
    acc += b2[j];
    float v = (acc > 0.f ? acc : 0.f) + H1s[r * 260 + j];
    Xs[r * 260 + j] = v;
  }
  __syncthreads();
  if (tid < 16) {
    float s = 0.f, s2 = 0.f;
    for (int k = 0; k < 256; ++k) { float x = Xs[tid * 260 + k]; s += x; s2 += x * x; }
    float mu = s * (1.0f / 256.0f);
    float var = s2 * (1.0f / 256.0f) - mu * mu;
    mu_s[tid] = mu; rs_s[tid] = rsqrtf(var + 1e-5f);
  }
  __syncthreads();
  for (int q = 0; q < 16; ++q) {
    float x = (Xs[q * 260 + tid] - mu_s[q]) * rs_s[q] * g[tid] + beta[tid];
    out_f32[(r0 + q) * 256 + tid] = x;
    if (out_bf16) out_bf16[(r0 + q) * 256 + tid] = f2bf(x);
  }
}

// ---------------- start head ----------------
__global__ __launch_bounds__(1024) void shead_kernel(
    const float* __restrict__ h, const float* __restrict__ Wo, const float* __restrict__ bo,
    float* __restrict__ start)
{
  __shared__ float red[16];
  __shared__ float lse_s;
  int tid = threadIdx.x;
  const float4* wr = (const float4*)Wo;
  const float4* hr = (const float4*)(h + tid * 256);
  float acc = 0.f;
  for (int kq = 0; kq < 64; ++kq) {
    float4 w = wr[kq], x = hr[kq];
    acc += w.x * x.x + w.y * x.y + w.z * x.z + w.w * x.w;
  }
  acc += bo[0];
  float s = __expf(acc);
  for (int m = 1; m < 64; m <<= 1) s += __shfl_xor(s, m);
  if ((tid & 63) == 0) red[tid >> 6] = s;
  __syncthreads();
  if (tid == 0) {
    float t = 0.f;
    for (int w = 0; w < 16; ++w) t += red[w];
    lse_s = logf(t);
  }
  __syncthreads();
  start[tid] = acc - lse_s;
}

// ---------------- bf16 MFMA GEMM, tile 64x32, K=256, D = A @ B^T ----------------
__global__ __launch_bounds__(256) void gemm_kernel(
    const ushort* __restrict__ A, const ushort* __restrict__ Bw,
    int mode, int Nvalid,
    const float* __restrict__ bias,
    float* __restrict__ out, float* __restrict__ esum, const int* __restrict__ text)
{
  __shared__ ushort As[64 * 264];
  __shared__ ushort Bs[32 * 264];
  int tid = threadIdx.x;
  int m0 = blockIdx.x * 64, n0 = blockIdx.y * 32;
#pragma unroll
  for (int q = 0; q < 8; ++q) {
    int idx = q * 256 + tid;
    int row = idx >> 5, c8 = idx & 31;
    *(short8*)(As + row * 264 + c8 * 8) = *(const short8*)(A + (m0 + row) * 256 + c8 * 8);
  }
#pragma unroll
  for (int q = 0; q < 4; ++q) {
    int idx = q * 256 + tid;
    int row = idx >> 5, c8 = idx & 31;
    int grow = n0 + row;
    short8 val = {0, 0, 0, 0, 0, 0, 0, 0};
    if (mode == 2) {
      int v = text[(grow & 15) * 256 + (grow >> 4)];
      val = *(const short8*)(Bw + v * 256 + c8 * 8);
    } else if (grow < Nvalid) {
      val = *(const short8*)(Bw + grow * 256 + c8 * 8);
    }
    *(short8*)(Bs + row * 264 + c8 * 8) = val;
  }
  __syncthreads();
  int lane = tid & 63, wave = tid >> 6;
  int r16 = lane & 15, quad = lane >> 4;
  f32x4 acc0 = {0.f, 0.f, 0.f, 0.f}, acc1 = {0.f, 0.f, 0.f, 0.f};
#pragma unroll
  for (int kb = 0; kb < 8; ++kb) {
    short8 a  = *(const short8*)(As + (wave * 16 + r16) * 264 + kb * 32 + quad * 8);
    short8 b0 = *(const short8*)(Bs + r16 * 264 + kb * 32 + quad * 8);
    short8 b1 = *(const short8*)(Bs + (16 + r16) * 264 + kb * 32 + quad * 8);
    acc0 = __builtin_amdgcn_mfma_f32_16x16x32_bf16(a, b0, acc0, 0, 0, 0);
    acc1 = __builtin_amdgcn_mfma_f32_16x16x32_bf16(a, b1, acc1, 0, 0, 0);
  }
  if (mode == 0) {
#pragma unroll
    for (int rr = 0; rr < 4; ++rr) {
      int row = m0 + wave * 16 + quad * 4 + rr;
      int c0 = n0 + r16, c1 = n0 + 16 + r16;
      out[row * 1024 + c0] = acc0[rr] + bias[c0];
      out[row * 1024 + c1] = acc1[rr] + bias[c1];
    }
  } else if (mode == 1) {
    float sums[4];
#pragma unroll
    for (int rr = 0; rr < 4; ++rr) {
      int c0 = n0 + r16, c1 = n0 + 16 + r16;
      float p0 = (c0 < Nvalid) ? __expf(acc0[rr] + bias[c0]) : 0.f;
      float p1 = (c1 < Nvalid) ? __expf(acc1[rr] + bias[c1]) : 0.f;
      float s = p0 + p1;
      s += __shfl_xor(s, 1); s += __shfl_xor(s, 2);
      s += __shfl_xor(s, 4); s += __shfl_xor(s, 8);
      sums[rr] = s;
    }
    if (r16 == 0) {
#pragma unroll
      for (int rr = 0; rr < 4; ++rr)
        atomicAdd(esum + m0 + wave * 16 + quad * 4 + rr, sums[rr]);
    }
  } else {
    int c0 = m0 + wave * 16 + quad * 4;
    int tb0 = n0 + r16, tb1 = n0 + 16 + r16;
    int v0 = text[(tb0 & 15) * 256 + (tb0 >> 4)];
    int v1 = text[(tb1 & 15) * 256 + (tb1 >> 4)];
    float l0 = logf(esum[c0]), l1 = logf(esum[c0 + 1]);
    float l2 = logf(esum[c0 + 2]), l3 = logf(esum[c0 + 3]);
    float4 o0, o1;
    o0.x = acc0[0] + bias[v0] - l0; o0.y = acc0[1] + bias[v0] - l1;
    o0.z = acc0[2] + bias[v0] - l2; o0.w = acc0[3] + bias[v0] - l3;
    o1.x = acc1[0] + bias[v1] - l0; o1.y = acc1[1] + bias[v1] - l1;
    o1.z = acc1[2] + bias[v1] - l2; o1.w = acc1[3] + bias[v1] - l3;
    *(float4*)(out + tb0 * 1024 + c0) = o0;
    *(float4*)(out + tb1 * 1024 + c0) = o1;
  }
}

// ---------------- transition: per-row log_softmax, scatter exp(T) in B-fragment order ----------------
__global__ __launch_bounds__(256) void trans_kernel(
    const float* __restrict__ logits, ushort* __restrict__ texp_frag)
{
  __shared__ float red[4];
  __shared__ float lse_s;
  int i = blockIdx.x, tid = threadIdx.x;
  float x[4];
  float s = 0.f;
#pragma unroll
  for (int q = 0; q < 4; ++q) { x[q] = logits[i * 1024 + q * 256 + tid]; s += __expf(x[q]); }
  for (int m = 1; m < 64; m <<= 1) s += __shfl_xor(s, m);
  if ((tid & 63) == 0) red[tid >> 6] = s;
  __syncthreads();
  if (tid == 0) lse_s = logf(red[0] + red[1] + red[2] + red[3]);
  __syncthreads();
  float lse = lse_s;
  int kblk = i >> 5, quad = (i >> 3) & 3, idx = i & 7;
#pragma unroll
  for (int q = 0; q < 4; ++q) {
    int j = q * 256 + tid;
    int pos = (((j >> 4) * 32 + kblk) * 64 + quad * 16 + (j & 15)) * 8 + idx;
    texp_frag[pos] = f2bf(__expf(x[q] - lse));
  }
}

// ---------------- alpha0 = start + emit[t=0] ----------------
__global__ void alpha0_kernel(const float* __restrict__ start, const float* __restrict__ emitg,
                              float* __restrict__ alpha)
{
  int i = blockIdx.x * 256 + threadIdx.x;
  alpha[i] = start[i & 1023] + emitg[i];
}

// ---------------- persistent forward scan: 255 steps ----------------
// Sync redesign vs R1:
//  - alpha read/write via agent-scope RELAXED atomics (global_load/store sc0 sc1:
//    bypass L1/L2, hit LLC directly) -> NO acquire buffer_inv -> Texp stays L2-hot.
//  - per-block flag word flags[p]=t instead of 64 contended atomicAdds on one line.
//  - release = s_waitcnt vmcnt(0) after write-through stores, then flag store.
__global__ __launch_bounds__(256, 1) void scan_kernel(
    const ushort* __restrict__ texp_frag,
    const float* __restrict__ emitg,
    float* __restrict__ alpha,          // [2][16*1024]
    unsigned int* __restrict__ flags)   // [64], zeroed
{
  __shared__ ushort aexp[16 * 1032];
  __shared__ float redw[4][16];
  __shared__ float mrow[16];
  __shared__ float ksum[3 * 256];
  int tid = threadIdx.x;
  int lane = tid & 63, wave = tid >> 6;
  int r16 = lane & 15, quad = lane >> 4;
  int p = blockIdx.x;

  for (int t = 1; t < 256; ++t) {
    if (t > 1) {
      unsigned want = (unsigned)(t - 1);
      while (__hip_atomic_load(flags + (tid & 63), __ATOMIC_RELAXED,
                               __HIP_MEMORY_SCOPE_AGENT) < want)
        __builtin_amdgcn_s_sleep(1);
    }
    __syncthreads();

    // read alpha[t-1] fresh from LLC (cache-bypassing relaxed atomics)
    const u64* a8 = (const u64*)(alpha + ((t - 1) & 1) * 16384);
    float4 v[16];
    float rm[16];
#pragma unroll
    for (int q = 0; q < 16; ++q) {
      u64 lo = __hip_atomic_load(a8 + q * 512 + tid * 2,     __ATOMIC_RELAXED, __HIP_MEMORY_SCOPE_AGENT);
      u64 hi = __hip_atomic_load(a8 + q * 512 + tid * 2 + 1, __ATOMIC_RELAXED, __HIP_MEMORY_SCOPE_AGENT);
      union { u64 u; float f[2]; } c0, c1;
      c0.u = lo; c1.u = hi;
      v[q].x = c0.f[0]; v[q].y = c0.f[1]; v[q].z = c1.f[0]; v[q].w = c1.f[1];
      rm[q] = fmaxf(fmaxf(v[q].x, v[q].y), fmaxf(v[q].z, v[q].w));
    }
#pragma unroll
    for (int q = 0; q < 16; ++q)
      for (int m = 1; m < 64; m <<= 1) rm[q] = fmaxf(rm[q], __shfl_xor(rm[q], m));
    if (lane == 0) {
#pragma unroll
      for (int q = 0; q < 16; ++q) redw[wave][q] = rm[q];
    }
    __syncthreads();
    float m16[16];
#pragma unroll
    for (int q = 0; q < 16; ++q)
      m16[q] = fmaxf(fmaxf(redw[0][q], redw[1][q]), fmaxf(redw[2][q], redw[3][q]));
    if (tid < 16)
      mrow[tid] = fmaxf(fmaxf(redw[0][tid], redw[1][tid]), fmaxf(redw[2][tid], redw[3][tid]));
#pragma unroll
    for (int q = 0; q < 16; ++q) {
      ushort4 u;
      u.x = f2bf(__expf(v[q].x - m16[q]));
      u.y = f2bf(__expf(v[q].y - m16[q]));
      u.z = f2bf(__expf(v[q].z - m16[q]));
      u.w = f2bf(__expf(v[q].w - m16[q]));
      *(ushort4*)(aexp + q * 1032 + 4 * tid) = u;
    }
    __syncthreads();

    // 4-wave split-K MFMA: D[b][j] = sum_i aexp[b][i] * Texp[i][j]
    f32x4 acc = {0.f, 0.f, 0.f, 0.f};
    const short8* tf = (const short8*)texp_frag;
#pragma unroll
    for (int it = 0; it < 8; ++it) {
      int k = wave * 8 + it;
      short8 a = *(const short8*)(aexp + r16 * 1032 + k * 32 + quad * 8);
      short8 b = tf[(p * 32 + k) * 64 + lane];
      acc = __builtin_amdgcn_mfma_f32_16x16x32_bf16(a, b, acc, 0, 0, 0);
    }
    if (wave != 0) *(f32x4*)(ksum + (wave - 1) * 256 + lane * 4) = acc;
    __syncthreads();
    if (wave == 0) {
      f32x4 s1 = *(const f32x4*)(ksum + 0 * 256 + lane * 4);
      f32x4 s2 = *(const f32x4*)(ksum + 1 * 256 + lane * 4);
      f32x4 s3 = *(const f32x4*)(ksum + 2 * 256 + lane * 4);
      acc = acc + s1 + s2 + s3;
      int jg = p * 16 + r16;
      float* aout = alpha + (t & 1) * 16384;
#pragma unroll
      for (int rr = 0; rr < 4; ++rr) {
        int b = quad * 4 + rr;
        float val = mrow[b] + logf(acc[rr]) + emitg[(t * 16 + b) * 1024 + jg];
        __hip_atomic_store(aout + b * 1024 + jg, val, __ATOMIC_RELAXED, __HIP_MEMORY_SCOPE_AGENT);
      }
      // release: write-through stores are at LLC once vmcnt retires
      asm volatile("s_waitcnt vmcnt(0)" ::: "memory");
      if (lane == 0)
        __hip_atomic_store(flags + p, (unsigned)t, __ATOMIC_RELAXED, __HIP_MEMORY_SCOPE_AGENT);
    }
  }
}

// ---------------- final: sum_b logsumexp_j(alpha_N[b,j]) ----------------
__global__ __launch_bounds__(256) void final_kernel(const float* __restrict__ alphaN,
                                                    float* __restrict__ out)
{
  __shared__ float red[4];
  int tid = threadIdx.x, lane = tid & 63, wave = tid >> 6;
  float total = 0.f;
  for (int b = 0; b < 16; ++b) {
    float4 v = ((const float4*)(alphaN + b * 1024))[tid];
    float mx = fmaxf(fmaxf(v.x, v.y), fmaxf(v.z, v.w));
    for (int m = 1; m < 64; m <<= 1) mx = fmaxf(mx, __shfl_xor(mx, m));
    if (lane == 0) red[wave] = mx;
    __syncthreads();
    mx = fmaxf(fmaxf(red[0], red[1]), fmaxf(red[2], red[3]));
    __syncthreads();
    float s = __expf(v.x - mx) + __expf(v.y - mx) + __expf(v.z - mx) + __expf(v.w - mx);
    for (int m = 1; m < 64; m <<= 1) s += __shfl_xor(s, m);
    if (lane == 0) red[wave] = s;
    __syncthreads();
    s = red[0] + red[1] + red[2] + red[3];
    total += mx + logf(s);
    __syncthreads();
  }
  if (tid == 0) out[0] = total;
}

extern "C" void kernel_launch(void* const* d_in, const int* in_sizes, int n_in,
                              void* d_out, int out_size, void* d_ws, size_t ws_size,
                              hipStream_t stream)
{
  (void)in_sizes; (void)n_in; (void)out_size; (void)ws_size;
  const float* start_emb = (const float*)d_in[0];
  const float* state_emb = (const float*)d_in[1];
  const float* pre_emb   = (const float*)d_in[2];
  const float* s_W1 = (const float*)d_in[3];  const float* s_b1 = (const float*)d_in[4];
  const float* s_W2 = (const float*)d_in[5];  const float* s_b2 = (const float*)d_in[6];
  const float* s_g  = (const float*)d_in[7];  const float* s_be = (const float*)d_in[8];
  const float* s_Wo = (const float*)d_in[9];  const float* s_bo = (const float*)d_in[10];
  const float* t_W1 = (const float*)d_in[11]; const float* t_b1 = (const float*)d_in[12];
  const float* t_W2 = (const float*)d_in[13]; const float* t_b2 = (const float*)d_in[14];
  const float* t_g  = (const float*)d_in[15]; const float* t_be = (const float*)d_in[16];
  const float* t_Wo = (const float*)d_in[17]; const float* t_bo = (const float*)d_in[18];
  const float* e_W1 = (const float*)d_in[19]; const float* e_b1 = (const float*)d_in[20];
  const float* e_W2 = (const float*)d_in[21]; const float* e_b2 = (const float*)d_in[22];
  const float* e_g  = (const float*)d_in[23]; const float* e_be = (const float*)d_in[24];
  const float* e_Wo = (const float*)d_in[25]; const float* e_bo = (const float*)d_in[26];
  const int*   text = (const int*)d_in[27];
  float* out = (float*)d_out;

  char* ws = (char*)d_ws;
  size_t off = 0;
  auto alloc = [&](size_t bytes) -> char* {
    char* p = ws + off;
    off = (off + bytes + 255) & ~(size_t)255;
    return p;
  };
  unsigned int* flags = (unsigned int*)alloc(256 * 4);
  float* esum       = (float*)alloc(1024 * 4);
  float* start_v    = (float*)alloc(1024 * 4);
  float* alpha      = (float*)alloc(2 * 16 * 1024 * 4);
  float* h_s        = (float*)alloc(1024 * 256 * 4);
  float* h_t        = (float*)alloc(1024 * 256 * 4);
  float* h_e        = (float*)alloc(1024 * 256 * 4);
  ushort* h_t_bf    = (ushort*)alloc(1024 * 256 * 2);
  ushort* h_e_bf    = (ushort*)alloc(1024 * 256 * 2);
  ushort* tWo_bf    = (ushort*)alloc(1024 * 256 * 2);
  ushort* eWo_bf    = (ushort*)alloc(10000 * 256 * 2);
  float* tlogits    = (float*)alloc(1024 * 1024 * 4);
  ushort* texp_frag = (ushort*)alloc(1024 * 1024 * 2);
  float* emitg      = (float*)alloc(4096 * 1024 * 4);

  hipMemsetAsync(ws, 0, 5120, stream);  // flags + esum

  cast_kernel<<<256, 256, 0, stream>>>(t_Wo, tWo_bf, 1024 * 256);
  cast_kernel<<<512, 256, 0, stream>>>(e_Wo, eWo_bf, 10000 * 256);

  mlp_kernel<<<64, 256, 0, stream>>>(start_emb, s_W1, s_b1, s_W2, s_b2, s_g, s_be, h_s, nullptr);
  mlp_kernel<<<64, 256, 0, stream>>>(state_emb, t_W1, t_b1, t_W2, t_b2, t_g, t_be, h_t, h_t_bf);
  mlp_kernel<<<64, 256, 0, stream>>>(pre_emb,  e_W1, e_b1, e_W2, e_b2, e_g, e_be, h_e, h_e_bf);

  shead_kernel<<<1, 1024, 0, stream>>>(h_s, s_Wo, s_bo, start_v);

  gemm_kernel<<<dim3(16, 32),  256, 0, stream>>>(h_t_bf, tWo_bf, 0, 1024,  t_bo, tlogits, nullptr, nullptr);
  trans_kernel<<<1024, 256, 0, stream>>>(tlogits, texp_frag);
  gemm_kernel<<<dim3(16, 313), 256, 0, stream>>>(h_e_bf, eWo_bf, 1, 10000, e_bo, nullptr, esum, nullptr);
  gemm_kernel<<<dim3(16, 128), 256, 0, stream>>>(h_e_bf, eWo_bf, 2, 4096,  e_bo, emitg, esum, text);

  alpha0_kernel<<<64, 256, 0, stream>>>(start_v, emitg, alpha);
  scan_kernel<<<GBLK, 256, 0, stream>>>(texp_frag, emitg, alpha, flags);
  final_kernel<<<1, 256, 0, stream>>>(alpha + 16384, out);
}

// Round 3
// 2528.359 us; speedup vs baseline: 1.0753x; 1.0519x over previous
//
#include <hip/hip_runtime.h>
#include <hip/hip_bf16.h>

typedef __attribute__((ext_vector_type(8))) short short8;
typedef __attribute__((ext_vector_type(4))) float f32x4;
typedef unsigned short ushort;
typedef unsigned long long u64;
typedef unsigned int u32;

#define GBLK 64   // persistent scan blocks

__device__ inline ushort f2bf(float x) {
  __hip_bfloat16 h = __float2bfloat16(x);
  return *reinterpret_cast<ushort*>(&h);
}
__device__ inline float bfhi2f(u32 lo) {           // high 16 bits as bf16
  union { u32 u; float f; } c; c.u = lo & 0xFFFF0000u; return c.f;
}
__device__ inline float bflo2f(u32 lo) {           // low 16 bits as bf16
  union { u32 u; float f; } c; c.u = lo << 16; return c.f;
}

// ---------------- cast f32 -> bf16 ----------------
__global__ void cast_kernel(const float* __restrict__ in, ushort* __restrict__ out, int n) {
  int i = blockIdx.x * blockDim.x + threadIdx.x;
  int stride = gridDim.x * blockDim.x;
  for (; i < n; i += stride) out[i] = f2bf(in[i]);
}

// ---------------- residual MLP: ln(relu(W2 relu(W1 x)) + relu(W1 x)) ----------------
__global__ __launch_bounds__(256) void mlp_kernel(
    const float* __restrict__ X,
    const float* __restrict__ W1, const float* __restrict__ b1,
    const float* __restrict__ W2, const float* __restrict__ b2,
    const float* __restrict__ g, const float* __restrict__ beta,
    float* __restrict__ out_f32, ushort* __restrict__ out_bf16)
{
  __shared__ float Xs[16 * 260];
  __shared__ float H1s[16 * 260];
  __shared__ float mu_s[16], rs_s[16];
  int tid = threadIdx.x;
  int r0 = blockIdx.x * 16;
  for (int q = 0; q < 16; ++q) Xs[q * 260 + tid] = X[(r0 + q) * 256 + tid];
  __syncthreads();
  int r = tid & 15, jg = tid >> 4;
  for (int jj = 0; jj < 16; ++jj) {
    int j = jg * 16 + jj;
    const float4* wrow = (const float4*)(W1 + j * 256);
    const float4* xrow = (const float4*)(Xs + r * 260);
    float acc = 0.f;
#pragma unroll 8
    for (int kq = 0; kq < 64; ++kq) {
      float4 w = wrow[kq], x = xrow[kq];
      acc += w.x * x.x + w.y * x.y + w.z * x.z + w.w * x.w;
    }
    acc += b1[j];
    H1s[r * 260 + j] = acc > 0.f ? acc : 0.f;
  }
  __syncthreads();
  for (int jj = 0; jj < 16; ++jj) {
    int j = jg * 16 + jj;
    const float4* wrow = (const float4*)(W2 + j * 256);
    const float4* hrow = (const float4*)(H1s + r * 260);
    float acc = 0.f;
#pragma unroll 8
    for (int kq = 0; kq < 64; ++kq) {
      float4 w = wrow[kq], x = hrow[kq];
      acc += w.x * x.x + w.y * x.y + w.z * x.z + w.w * x.w;
    }
    acc += b2[j];
    float v = (acc > 0.f ? acc : 0.f) + H1s[r * 260 + j];
    Xs[r * 260 + j] = v;
  }
  __syncthreads();
  if (tid < 16) {
    float s = 0.f, s2 = 0.f;
    for (int k = 0; k < 256; ++k) { float x = Xs[tid * 260 + k]; s += x; s2 += x * x; }
    float mu = s * (1.0f / 256.0f);
    float var = s2 * (1.0f / 256.0f) - mu * mu;
    mu_s[tid] = mu; rs_s[tid] = rsqrtf(var + 1e-5f);
  }
  __syncthreads();
  for (int q = 0; q < 16; ++q) {
    float x = (Xs[q * 260 + tid] - mu_s[q]) * rs_s[q] * g[tid] + beta[tid];
    out_f32[(r0 + q) * 256 + tid] = x;
    if (out_bf16) out_bf16[(r0 + q) * 256 + tid] = f2bf(x);
  }
}

// ---------------- start head ----------------
__global__ __launch_bounds__(1024) void shead_kernel(
    const float* __restrict__ h, const float* __restrict__ Wo, const float* __restrict__ bo,
    float* __restrict__ start)
{
  __shared__ float red[16];
  __shared__ float lse_s;
  int tid = threadIdx.x;
  const float4* wr = (const float4*)Wo;
  const float4* hr = (const float4*)(h + tid * 256);
  float acc = 0.f;
  for (int kq = 0; kq < 64; ++kq) {
    float4 w = wr[kq], x = hr[kq];
    acc += w.x * x.x + w.y * x.y + w.z * x.z + w.w * x.w;
  }
  acc += bo[0];
  float s = __expf(acc);
  for (int m = 1; m < 64; m <<= 1) s += __shfl_xor(s, m);
  if ((tid & 63) == 0) red[tid >> 6] = s;
  __syncthreads();
  if (tid == 0) {
    float t = 0.f;
    for (int w = 0; w < 16; ++w) t += red[w];
    lse_s = logf(t);
  }
  __syncthreads();
  start[tid] = acc - lse_s;
}

// ---------------- bf16 MFMA GEMM, tile 64x32, K=256, D = A @ B^T ----------------
__global__ __launch_bounds__(256) void gemm_kernel(
    const ushort* __restrict__ A, const ushort* __restrict__ Bw,
    int mode, int Nvalid,
    const float* __restrict__ bias,
    float* __restrict__ out, float* __restrict__ esum, const int* __restrict__ text)
{
  __shared__ ushort As[64 * 264];
  __shared__ ushort Bs[32 * 264];
  int tid = threadIdx.x;
  int m0 = blockIdx.x * 64, n0 = blockIdx.y * 32;
#pragma unroll
  for (int q = 0; q < 8; ++q) {
    int idx = q * 256 + tid;
    int row = idx >> 5, c8 = idx & 31;
    *(short8*)(As + row * 264 + c8 * 8) = *(const short8*)(A + (m0 + row) * 256 + c8 * 8);
  }
#pragma unroll
  for (int q = 0; q < 4; ++q) {
    int idx = q * 256 + tid;
    int row = idx >> 5, c8 = idx & 31;
    int grow = n0 + row;
    short8 val = {0, 0, 0, 0, 0, 0, 0, 0};
    if (mode == 2) {
      int v = text[(grow & 15) * 256 + (grow >> 4)];
      val = *(const short8*)(Bw + v * 256 + c8 * 8);
    } else if (grow < Nvalid) {
      val = *(const short8*)(Bw + grow * 256 + c8 * 8);
    }
    *(short8*)(Bs + row * 264 + c8 * 8) = val;
  }
  __syncthreads();
  int lane = tid & 63, wave = tid >> 6;
  int r16 = lane & 15, quad = lane >> 4;
  f32x4 acc0 = {0.f, 0.f, 0.f, 0.f}, acc1 = {0.f, 0.f, 0.f, 0.f};
#pragma unroll
  for (int kb = 0; kb < 8; ++kb) {
    short8 a  = *(const short8*)(As + (wave * 16 + r16) * 264 + kb * 32 + quad * 8);
    short8 b0 = *(const short8*)(Bs + r16 * 264 + kb * 32 + quad * 8);
    short8 b1 = *(const short8*)(Bs + (16 + r16) * 264 + kb * 32 + quad * 8);
    acc0 = __builtin_amdgcn_mfma_f32_16x16x32_bf16(a, b0, acc0, 0, 0, 0);
    acc1 = __builtin_amdgcn_mfma_f32_16x16x32_bf16(a, b1, acc1, 0, 0, 0);
  }
  if (mode == 0) {
#pragma unroll
    for (int rr = 0; rr < 4; ++rr) {
      int row = m0 + wave * 16 + quad * 4 + rr;
      int c0 = n0 + r16, c1 = n0 + 16 + r16;
      out[row * 1024 + c0] = acc0[rr] + bias[c0];
      out[row * 1024 + c1] = acc1[rr] + bias[c1];
    }
  } else if (mode == 1) {
    float sums[4];
#pragma unroll
    for (int rr = 0; rr < 4; ++rr) {
      int c0 = n0 + r16, c1 = n0 + 16 + r16;
      float p0 = (c0 < Nvalid) ? __expf(acc0[rr] + bias[c0]) : 0.f;
      float p1 = (c1 < Nvalid) ? __expf(acc1[rr] + bias[c1]) : 0.f;
      float s = p0 + p1;
      s += __shfl_xor(s, 1); s += __shfl_xor(s, 2);
      s += __shfl_xor(s, 4); s += __shfl_xor(s, 8);
      sums[rr] = s;
    }
    if (r16 == 0) {
#pragma unroll
      for (int rr = 0; rr < 4; ++rr)
        atomicAdd(esum + m0 + wave * 16 + quad * 4 + rr, sums[rr]);
    }
  } else {
    int c0 = m0 + wave * 16 + quad * 4;
    int tb0 = n0 + r16, tb1 = n0 + 16 + r16;
    int v0 = text[(tb0 & 15) * 256 + (tb0 >> 4)];
    int v1 = text[(tb1 & 15) * 256 + (tb1 >> 4)];
    float l0 = logf(esum[c0]), l1 = logf(esum[c0 + 1]);
    float l2 = logf(esum[c0 + 2]), l3 = logf(esum[c0 + 3]);
    float4 o0, o1;
    o0.x = acc0[0] + bias[v0] - l0; o0.y = acc0[1] + bias[v0] - l1;
    o0.z = acc0[2] + bias[v0] - l2; o0.w = acc0[3] + bias[v0] - l3;
    o1.x = acc1[0] + bias[v1] - l0; o1.y = acc1[1] + bias[v1] - l1;
    o1.z = acc1[2] + bias[v1] - l2; o1.w = acc1[3] + bias[v1] - l3;
    *(float4*)(out + tb0 * 1024 + c0) = o0;
    *(float4*)(out + tb1 * 1024 + c0) = o1;
  }
}

// ---------------- transition: per-row log_softmax, scatter exp(T) in B-fragment order ----------------
__global__ __launch_bounds__(256) void trans_kernel(
    const float* __restrict__ logits, ushort* __restrict__ texp_frag)
{
  __shared__ float red[4];
  __shared__ float lse_s;
  int i = blockIdx.x, tid = threadIdx.x;
  float x[4];
  float s = 0.f;
#pragma unroll
  for (int q = 0; q < 4; ++q) { x[q] = logits[i * 1024 + q * 256 + tid]; s += __expf(x[q]); }
  for (int m = 1; m < 64; m <<= 1) s += __shfl_xor(s, m);
  if ((tid & 63) == 0) red[tid >> 6] = s;
  __syncthreads();
  if (tid == 0) lse_s = logf(red[0] + red[1] + red[2] + red[3]);
  __syncthreads();
  float lse = lse_s;
  int kblk = i >> 5, quad = (i >> 3) & 3, idx = i & 7;
#pragma unroll
  for (int q = 0; q < 4; ++q) {
    int j = q * 256 + tid;
    int pos = (((j >> 4) * 32 + kblk) * 64 + quad * 16 + (j & 15)) * 8 + idx;
    texp_frag[pos] = f2bf(__expf(x[q] - lse));
  }
}

// ---------------- delta_0 = start + emit[t=0], tagged t=0 ----------------
// abuf word: {bf16 d(col even), bf16 d(col odd)} | tag<<32
__global__ void alpha0_kernel(const float* __restrict__ start, const float* __restrict__ emitg,
                              u64* __restrict__ abuf)
{
  int i = blockIdx.x * 256 + threadIdx.x;   // 0..8191 = b*512 + c2
  int b = i >> 9, c2 = i & 511;
  int j = c2 * 2;
  float v0 = start[j]     + emitg[b * 1024 + j];
  float v1 = start[j + 1] + emitg[b * 1024 + j + 1];
  u32 lo = (u32)f2bf(v0) | ((u32)f2bf(v1) << 16);
  abuf[i] = (u64)lo;   // tag 0 in high 32 bits
}

// ---------------- persistent forward scan: 255 steps, tagged-dataflow sync ----------------
// Transmits delta_t = log(acc) + emit (small range -> bf16-safe); base
// B_t[b] = sum of per-step row maxes, tracked identically in-register by all blocks.
// No flags, no vmcnt release, no barrier: every 8B word self-validates via its tag.
__global__ __launch_bounds__(256, 1) void scan_kernel(
    const ushort* __restrict__ texp_frag,
    const float* __restrict__ emitg,
    u64* __restrict__ abuf,             // [2][16*512] u64
    float* __restrict__ out)
{
  __shared__ ushort aexp[16 * 1032];
  __shared__ float redw[4][16];
  __shared__ float ksum[3 * 256];
  int tid = threadIdx.x;
  int lane = tid & 63, wave = tid >> 6;
  int r16 = lane & 15, quad = lane >> 4;
  int p = blockIdx.x;

  float Bsum[16];
#pragma unroll
  for (int q = 0; q < 16; ++q) Bsum[q] = 0.f;

  u64 d[32];
  float m16[16];

  for (int t = 1; t < 256; ++t) {
    // prefetch emission for this step's epilogue (only wave0 consumes)
    float emit_pre[4];
    if (wave == 0) {
#pragma unroll
      for (int rr = 0; rr < 4; ++rr)
        emit_pre[rr] = emitg[(t * 16 + quad * 4 + rr) * 1024 + p * 16 + r16];
    }

    // ---- poll previous delta (tagged): batched loads, retry stale ----
    u32 want = (u32)(t - 1);
    const u64* buf = abuf + ((t - 1) & 1) * 8192;
    u32 pend = 0xFFFFFFFFu;
    bool first = true;
    while (pend) {
      if (!first) __builtin_amdgcn_s_sleep(1);
      first = false;
      u64 x[32];
#pragma unroll
      for (int i = 0; i < 32; ++i) {
        if (pend & (1u << i))
          x[i] = __hip_atomic_load(buf + (i >> 1) * 512 + tid * 2 + (i & 1),
                                   __ATOMIC_RELAXED, __HIP_MEMORY_SCOPE_AGENT);
      }
#pragma unroll
      for (int i = 0; i < 32; ++i) {
        if ((pend & (1u << i)) && (u32)(x[i] >> 32) == want) {
          d[i] = x[i];
          pend &= ~(1u << i);
        }
      }
    }

    // ---- unpack + per-row max ----
    float v[16][4];
    float rm[16];
#pragma unroll
    for (int q = 0; q < 16; ++q) {
      u32 lo0 = (u32)d[2 * q], lo1 = (u32)d[2 * q + 1];
      v[q][0] = bflo2f(lo0); v[q][1] = bfhi2f(lo0);
      v[q][2] = bflo2f(lo1); v[q][3] = bfhi2f(lo1);
      rm[q] = fmaxf(fmaxf(v[q][0], v[q][1]), fmaxf(v[q][2], v[q][3]));
    }
#pragma unroll
    for (int q = 0; q < 16; ++q)
      for (int m = 1; m < 64; m <<= 1) rm[q] = fmaxf(rm[q], __shfl_xor(rm[q], m));
    if (lane == 0) {
#pragma unroll
      for (int q = 0; q < 16; ++q) redw[wave][q] = rm[q];
    }
    __syncthreads();
#pragma unroll
    for (int q = 0; q < 16; ++q) {
      m16[q] = fmaxf(fmaxf(redw[0][q], redw[1][q]), fmaxf(redw[2][q], redw[3][q]));
      Bsum[q] += m16[q];
    }
    // ---- exp + pack to LDS A-fragments ----
#pragma unroll
    for (int q = 0; q < 16; ++q) {
      ushort4 u;
      u.x = f2bf(__expf(v[q][0] - m16[q]));
      u.y = f2bf(__expf(v[q][1] - m16[q]));
      u.z = f2bf(__expf(v[q][2] - m16[q]));
      u.w = f2bf(__expf(v[q][3] - m16[q]));
      *(ushort4*)(aexp + q * 1032 + 4 * tid) = u;
    }
    __syncthreads();

    // ---- 4-wave split-K MFMA: D[b][j] = sum_i aexp[b][i] * Texp[i][j] ----
    f32x4 acc = {0.f, 0.f, 0.f, 0.f};
    const short8* tf = (const short8*)texp_frag;
#pragma unroll
    for (int it = 0; it < 8; ++it) {
      int k = wave * 8 + it;
      short8 a = *(const short8*)(aexp + r16 * 1032 + k * 32 + quad * 8);
      short8 b = tf[(p * 32 + k) * 64 + lane];
      acc = __builtin_amdgcn_mfma_f32_16x16x32_bf16(a, b, acc, 0, 0, 0);
    }
    if (wave != 0) *(f32x4*)(ksum + (wave - 1) * 256 + lane * 4) = acc;
    __syncthreads();
    if (wave == 0) {
      f32x4 s1 = *(const f32x4*)(ksum + 0 * 256 + lane * 4);
      f32x4 s2 = *(const f32x4*)(ksum + 1 * 256 + lane * 4);
      f32x4 s3 = *(const f32x4*)(ksum + 2 * 256 + lane * 4);
      acc = acc + s1 + s2 + s3;
      // delta = log(acc) + emit  (base tracked in Bsum, NOT added)
      float dv[4], pv[4];
#pragma unroll
      for (int rr = 0; rr < 4; ++rr) dv[rr] = logf(acc[rr]) + emit_pre[rr];
#pragma unroll
      for (int rr = 0; rr < 4; ++rr) pv[rr] = __shfl_xor(dv[rr], 1);
      if ((lane & 1) == 0) {
        u64* ob = abuf + (t & 1) * 8192;
        int c2 = p * 8 + (r16 >> 1);
        u64 tag = ((u64)(u32)t) << 32;
#pragma unroll
        for (int rr = 0; rr < 4; ++rr) {
          u32 lo = (u32)f2bf(dv[rr]) | ((u32)f2bf(pv[rr]) << 16);
          __hip_atomic_store(ob + (quad * 4 + rr) * 512 + c2, tag | (u64)lo,
                             __ATOMIC_RELAXED, __HIP_MEMORY_SCOPE_AGENT);
        }
      }
    }
  }

  // ---- final reduction (block 0): out = sum_b [B_255[b] + lse_j delta_255[b,j]] ----
  if (p == 0) {
    u32 want = 255;
    const u64* buf = abuf + 8192;   // parity 1
    u32 pend = 0xFFFFFFFFu;
    bool first = true;
    while (pend) {
      if (!first) __builtin_amdgcn_s_sleep(1);
      first = false;
      u64 x[32];
#pragma unroll
      for (int i = 0; i < 32; ++i) {
        if (pend & (1u << i))
          x[i] = __hip_atomic_load(buf + (i >> 1) * 512 + tid * 2 + (i & 1),
                                   __ATOMIC_RELAXED, __HIP_MEMORY_SCOPE_AGENT);
      }
#pragma unroll
      for (int i = 0; i < 32; ++i) {
        if ((pend & (1u << i)) && (u32)(x[i] >> 32) == want) {
          d[i] = x[i];
          pend &= ~(1u << i);
        }
      }
    }
    float v[16][4], rm[16];
#pragma unroll
    for (int q = 0; q < 16; ++q) {
      u32 lo0 = (u32)d[2 * q], lo1 = (u32)d[2 * q + 1];
      v[q][0] = bflo2f(lo0); v[q][1] = bfhi2f(lo0);
      v[q][2] = bflo2f(lo1); v[q][3] = bfhi2f(lo1);
      rm[q] = fmaxf(fmaxf(v[q][0], v[q][1]), fmaxf(v[q][2], v[q][3]));
    }
#pragma unroll
    for (int q = 0; q < 16; ++q)
      for (int m = 1; m < 64; m <<= 1) rm[q] = fmaxf(rm[q], __shfl_xor(rm[q], m));
    if (lane == 0) {
#pragma unroll
      for (int q = 0; q < 16; ++q) redw[wave][q] = rm[q];
    }
    __syncthreads();
#pragma unroll
    for (int q = 0; q < 16; ++q)
      m16[q] = fmaxf(fmaxf(redw[0][q], redw[1][q]), fmaxf(redw[2][q], redw[3][q]));
    __syncthreads();
    float sq[16];
#pragma unroll
    for (int q = 0; q < 16; ++q) {
      sq[q] = __expf(v[q][0] - m16[q]) + __expf(v[q][1] - m16[q]) +
              __expf(v[q][2] - m16[q]) + __expf(v[q][3] - m16[q]);
      for (int m = 1; m < 64; m <<= 1) sq[q] += __shfl_xor(sq[q], m);
    }
    if (lane == 0) {
#pragma unroll
      for (int q = 0; q < 16; ++q) redw[wave][q] = sq[q];
    }
    __syncthreads();
    if (tid == 0) {
      float total = 0.f;
#pragma unroll
      for (int q = 0; q < 16; ++q)
        total += Bsum[q] + m16[q] +
                 logf(redw[0][q] + redw[1][q] + redw[2][q] + redw[3][q]);
      out[0] = total;
    }
  }
}

extern "C" void kernel_launch(void* const* d_in, const int* in_sizes, int n_in,
                              void* d_out, int out_size, void* d_ws, size_t ws_size,
                              hipStream_t stream)
{
  (void)in_sizes; (void)n_in; (void)out_size; (void)ws_size;
  const float* start_emb = (const float*)d_in[0];
  const float* state_emb = (const float*)d_in[1];
  const float* pre_emb   = (const float*)d_in[2];
  const float* s_W1 = (const float*)d_in[3];  const float* s_b1 = (const float*)d_in[4];
  const float* s_W2 = (const float*)d_in[5];  const float* s_b2 = (const float*)d_in[6];
  const float* s_g  = (const float*)d_in[7];  const float* s_be = (const float*)d_in[8];
  const float* s_Wo = (const float*)d_in[9];  const float* s_bo = (const float*)d_in[10];
  const float* t_W1 = (const float*)d_in[11]; const float* t_b1 = (const float*)d_in[12];
  const float* t_W2 = (const float*)d_in[13]; const float* t_b2 = (const float*)d_in[14];
  const float* t_g  = (const float*)d_in[15]; const float* t_be = (const float*)d_in[16];
  const float* t_Wo = (const float*)d_in[17]; const float* t_bo = (const float*)d_in[18];
  const float* e_W1 = (const float*)d_in[19]; const float* e_b1 = (const float*)d_in[20];
  const float* e_W2 = (const float*)d_in[21]; const float* e_b2 = (const float*)d_in[22];
  const float* e_g  = (const float*)d_in[23]; const float* e_be = (const float*)d_in[24];
  const float* e_Wo = (const float*)d_in[25]; const float* e_bo = (const float*)d_in[26];
  const int*   text = (const int*)d_in[27];
  float* out = (float*)d_out;

  char* ws = (char*)d_ws;
  size_t off = 0;
  auto alloc = [&](size_t bytes) -> char* {
    char* p = ws + off;
    off = (off + bytes + 255) & ~(size_t)255;
    return p;
  };
  float* esum       = (float*)alloc(1024 * 4);             // @0 (memset below)
  u64* abuf         = (u64*)alloc(2 * 8192 * 8);           // tagged delta exchange
  float* start_v    = (float*)alloc(1024 * 4);
  float* h_s        = (float*)alloc(1024 * 256 * 4);
  float* h_t        = (float*)alloc(1024 * 256 * 4);
  float* h_e        = (float*)alloc(1024 * 256 * 4);
  ushort* h_t_bf    = (ushort*)alloc(1024 * 256 * 2);
  ushort* h_e_bf    = (ushort*)alloc(1024 * 256 * 2);
  ushort* tWo_bf    = (ushort*)alloc(1024 * 256 * 2);
  ushort* eWo_bf    = (ushort*)alloc(10000 * 256 * 2);
  float* tlogits    = (float*)alloc(1024 * 1024 * 4);
  ushort* texp_frag = (ushort*)alloc(1024 * 1024 * 2);
  float* emitg      = (float*)alloc(4096 * 1024 * 4);

  hipMemsetAsync(ws, 0, 4096, stream);  // esum

  cast_kernel<<<256, 256, 0, stream>>>(t_Wo, tWo_bf, 1024 * 256);
  cast_kernel<<<512, 256, 0, stream>>>(e_Wo, eWo_bf, 10000 * 256);

  mlp_kernel<<<64, 256, 0, stream>>>(start_emb, s_W1, s_b1, s_W2, s_b2, s_g, s_be, h_s, nullptr);
  mlp_kernel<<<64, 256, 0, stream>>>(state_emb, t_W1, t_b1, t_W2, t_b2, t_g, t_be, h_t, h_t_bf);
  mlp_kernel<<<64, 256, 0, stream>>>(pre_emb,  e_W1, e_b1, e_W2, e_b2, e_g, e_be, h_e, h_e_bf);

  shead_kernel<<<1, 1024, 0, stream>>>(h_s, s_Wo, s_bo, start_v);

  gemm_kernel<<<dim3(16, 32),  256, 0, stream>>>(h_t_bf, tWo_bf, 0, 1024,  t_bo, tlogits, nullptr, nullptr);
  trans_kernel<<<1024, 256, 0, stream>>>(tlogits, texp_frag);
  gemm_kernel<<<dim3(16, 313), 256, 0, stream>>>(h_e_bf, eWo_bf, 1, 10000, e_bo, nullptr, esum, nullptr);
  gemm_kernel<<<dim3(16, 128), 256, 0, stream>>>(h_e_bf, eWo_bf, 2, 4096,  e_bo, emitg, esum, text);

  alpha0_kernel<<<32, 256, 0, stream>>>(start_v, emitg, (u64*)abuf);
  scan_kernel<<<GBLK, 256, 0, stream>>>(texp_frag, emitg, abuf, out);
}

// Round 4
// 1523.329 us; speedup vs baseline: 1.7847x; 1.6598x over previous
//
#include <hip/hip_runtime.h>
#include <hip/hip_bf16.h>

typedef __attribute__((ext_vector_type(8))) short short8;
typedef __attribute__((ext_vector_type(4))) float f32x4;
typedef unsigned short ushort;
typedef unsigned long long u64;
typedef unsigned int u32;

#define GBLK 64   // 4 groups x 16 blocks; all co-resident on 256 CUs

__device__ inline ushort f2bf(float x) {
  __hip_bfloat16 h = __float2bfloat16(x);
  return *reinterpret_cast<ushort*>(&h);
}
__device__ inline float bfhi2f(u32 lo) {
  union { u32 u; float f; } c; c.u = lo & 0xFFFF0000u; return c.f;
}
__device__ inline float bflo2f(u32 lo) {
  union { u32 u; float f; } c; c.u = lo << 16; return c.f;
}

// ---------------- cast f32 -> bf16 ----------------
__global__ void cast_kernel(const float* __restrict__ in, ushort* __restrict__ out, int n) {
  int i = blockIdx.x * blockDim.x + threadIdx.x;
  int stride = gridDim.x * blockDim.x;
  for (; i < n; i += stride) out[i] = f2bf(in[i]);
}

// ---------------- residual MLP: ln(relu(W2 relu(W1 x)) + relu(W1 x)) ----------------
__global__ __launch_bounds__(256) void mlp_kernel(
    const float* __restrict__ X,
    const float* __restrict__ W1, const float* __restrict__ b1,
    const float* __restrict__ W2, const float* __restrict__ b2,
    const float* __restrict__ g, const float* __restrict__ beta,
    float* __restrict__ out_f32, ushort* __restrict__ out_bf16)
{
  __shared__ float Xs[16 * 260];
  __shared__ float H1s[16 * 260];
  __shared__ float mu_s[16], rs_s[16];
  int tid = threadIdx.x;
  int r0 = blockIdx.x * 16;
  for (int q = 0; q < 16; ++q) Xs[q * 260 + tid] = X[(r0 + q) * 256 + tid];
  __syncthreads();
  int r = tid & 15, jg = tid >> 4;
  for (int jj = 0; jj < 16; ++jj) {
    int j = jg * 16 + jj;
    const float4* wrow = (const float4*)(W1 + j * 256);
    const float4* xrow = (const float4*)(Xs + r * 260);
    float acc = 0.f;
#pragma unroll 8
    for (int kq = 0; kq < 64; ++kq) {
      float4 w = wrow[kq], x = xrow[kq];
      acc += w.x * x.x + w.y * x.y + w.z * x.z + w.w * x.w;
    }
    acc += b1[j];
    H1s[r * 260 + j] = acc > 0.f ? acc : 0.f;
  }
  __syncthreads();
  for (int jj = 0; jj < 16; ++jj) {
    int j = jg * 16 + jj;
    const float4* wrow = (const float4*)(W2 + j * 256);
    const float4* hrow = (const float4*)(H1s + r * 260);
    float acc = 0.f;
#pragma unroll 8
    for (int kq = 0; kq < 64; ++kq) {
      float4 w = wrow[kq], x = hrow[kq];
      acc += w.x * x.x + w.y * x.y + w.z * x.z + w.w * x.w;
    }
    acc += b2[j];
    float v = (acc > 0.f ? acc : 0.f) + H1s[r * 260 + j];
    Xs[r * 260 + j] = v;
  }
  __syncthreads();
  if (tid < 16) {
    float s = 0.f, s2 = 0.f;
    for (int k = 0; k < 256; ++k) { float x = Xs[tid * 260 + k]; s += x; s2 += x * x; }
    float mu = s * (1.0f / 256.0f);
    float var = s2 * (1.0f / 256.0f) - mu * mu;
    mu_s[tid] = mu; rs_s[tid] = rsqrtf(var + 1e-5f);
  }
  __syncthreads();
  for (int q = 0; q < 16; ++q) {
    float x = (Xs[q * 260 + tid] - mu_s[q]) * rs_s[q] * g[tid] + beta[tid];
    out_f32[(r0 + q) * 256 + tid] = x;
    if (out_bf16) out_bf16[(r0 + q) * 256 + tid] = f2bf(x);
  }
}

// ---------------- start head ----------------
__global__ __launch_bounds__(1024) void shead_kernel(
    const float* __restrict__ h, const float* __restrict__ Wo, const float* __restrict__ bo,
    float* __restrict__ start)
{
  __shared__ float red[16];
  __shared__ float lse_s;
  int tid = threadIdx.x;
  const float4* wr = (const float4*)Wo;
  const float4* hr = (const float4*)(h + tid * 256);
  float acc = 0.f;
  for (int kq = 0; kq < 64; ++kq) {
    float4 w = wr[kq], x = hr[kq];
    acc += w.x * x.x + w.y * x.y + w.z * x.z + w.w * x.w;
  }
  acc += bo[0];
  float s = __expf(acc);
  for (int m = 1; m < 64; m <<= 1) s += __shfl_xor(s, m);
  if ((tid & 63) == 0) red[tid >> 6] = s;
  __syncthreads();
  if (tid == 0) {
    float t = 0.f;
    for (int w = 0; w < 16; ++w) t += red[w];
    lse_s = logf(t);
  }
  __syncthreads();
  start[tid] = acc - lse_s;
}

// ---------------- bf16 MFMA GEMM, tile 64x32, K=256, D = A @ B^T ----------------
__global__ __launch_bounds__(256) void gemm_kernel(
    const ushort* __restrict__ A, const ushort* __restrict__ Bw,
    int mode, int Nvalid,
    const float* __restrict__ bias,
    float* __restrict__ out, float* __restrict__ esum, const int* __restrict__ text)
{
  __shared__ ushort As[64 * 264];
  __shared__ ushort Bs[32 * 264];
  int tid = threadIdx.x;
  int m0 = blockIdx.x * 64, n0 = blockIdx.y * 32;
#pragma unroll
  for (int q = 0; q < 8; ++q) {
    int idx = q * 256 + tid;
    int row = idx >> 5, c8 = idx & 31;
    *(short8*)(As + row * 264 + c8 * 8) = *(const short8*)(A + (m0 + row) * 256 + c8 * 8);
  }
#pragma unroll
  for (int q = 0; q < 4; ++q) {
    int idx = q * 256 + tid;
    int row = idx >> 5, c8 = idx & 31;
    int grow = n0 + row;
    short8 val = {0, 0, 0, 0, 0, 0, 0, 0};
    if (mode == 2) {
      int v = text[(grow & 15) * 256 + (grow >> 4)];
      val = *(const short8*)(Bw + v * 256 + c8 * 8);
    } else if (grow < Nvalid) {
      val = *(const short8*)(Bw + grow * 256 + c8 * 8);
    }
    *(short8*)(Bs + row * 264 + c8 * 8) = val;
  }
  __syncthreads();
  int lane = tid & 63, wave = tid >> 6;
  int r16 = lane & 15, quad = lane >> 4;
  f32x4 acc0 = {0.f, 0.f, 0.f, 0.f}, acc1 = {0.f, 0.f, 0.f, 0.f};
#pragma unroll
  for (int kb = 0; kb < 8; ++kb) {
    short8 a  = *(const short8*)(As + (wave * 16 + r16) * 264 + kb * 32 + quad * 8);
    short8 b0 = *(const short8*)(Bs + r16 * 264 + kb * 32 + quad * 8);
    short8 b1 = *(const short8*)(Bs + (16 + r16) * 264 + kb * 32 + quad * 8);
    acc0 = __builtin_amdgcn_mfma_f32_16x16x32_bf16(a, b0, acc0, 0, 0, 0);
    acc1 = __builtin_amdgcn_mfma_f32_16x16x32_bf16(a, b1, acc1, 0, 0, 0);
  }
  if (mode == 0) {
#pragma unroll
    for (int rr = 0; rr < 4; ++rr) {
      int row = m0 + wave * 16 + quad * 4 + rr;
      int c0 = n0 + r16, c1 = n0 + 16 + r16;
      out[row * 1024 + c0] = acc0[rr] + bias[c0];
      out[row * 1024 + c1] = acc1[rr] + bias[c1];
    }
  } else if (mode == 1) {
    float sums[4];
#pragma unroll
    for (int rr = 0; rr < 4; ++rr) {
      int c0 = n0 + r16, c1 = n0 + 16 + r16;
      float p0 = (c0 < Nvalid) ? __expf(acc0[rr] + bias[c0]) : 0.f;
      float p1 = (c1 < Nvalid) ? __expf(acc1[rr] + bias[c1]) : 0.f;
      float s = p0 + p1;
      s += __shfl_xor(s, 1); s += __shfl_xor(s, 2);
      s += __shfl_xor(s, 4); s += __shfl_xor(s, 8);
      sums[rr] = s;
    }
    if (r16 == 0) {
#pragma unroll
      for (int rr = 0; rr < 4; ++rr)
        atomicAdd(esum + m0 + wave * 16 + quad * 4 + rr, sums[rr]);
    }
  } else {
    int c0 = m0 + wave * 16 + quad * 4;
    int tb0 = n0 + r16, tb1 = n0 + 16 + r16;
    int v0 = text[(tb0 & 15) * 256 + (tb0 >> 4)];
    int v1 = text[(tb1 & 15) * 256 + (tb1 >> 4)];
    float l0 = logf(esum[c0]), l1 = logf(esum[c0 + 1]);
    float l2 = logf(esum[c0 + 2]), l3 = logf(esum[c0 + 3]);
    float4 o0, o1;
    o0.x = acc0[0] + bias[v0] - l0; o0.y = acc0[1] + bias[v0] - l1;
    o0.z = acc0[2] + bias[v0] - l2; o0.w = acc0[3] + bias[v0] - l3;
    o1.x = acc1[0] + bias[v1] - l0; o1.y = acc1[1] + bias[v1] - l1;
    o1.z = acc1[2] + bias[v1] - l2; o1.w = acc1[3] + bias[v1] - l3;
    *(float4*)(out + tb0 * 1024 + c0) = o0;
    *(float4*)(out + tb1 * 1024 + c0) = o1;
  }
}

// ---------------- transition: per-row log_softmax, scatter exp(T) in B-fragment order ----------------
// layout: [colblock j>>4][kblock i>>5][lane][8], lane = kquad*16 + (j&15)
__global__ __launch_bounds__(256) void trans_kernel(
    const float* __restrict__ logits, ushort* __restrict__ texp_frag)
{
  __shared__ float red[4];
  __shared__ float lse_s;
  int i = blockIdx.x, tid = threadIdx.x;
  float x[4];
  float s = 0.f;
#pragma unroll
  for (int q = 0; q < 4; ++q) { x[q] = logits[i * 1024 + q * 256 + tid]; s += __expf(x[q]); }
  for (int m = 1; m < 64; m <<= 1) s += __shfl_xor(s, m);
  if ((tid & 63) == 0) red[tid >> 6] = s;
  __syncthreads();
  if (tid == 0) lse_s = logf(red[0] + red[1] + red[2] + red[3]);
  __syncthreads();
  float lse = lse_s;
  int kblk = i >> 5, quad = (i >> 3) & 3, idx = i & 7;
#pragma unroll
  for (int q = 0; q < 4; ++q) {
    int j = q * 256 + tid;
    int pos = (((j >> 4) * 32 + kblk) * 64 + quad * 16 + (j & 15)) * 8 + idx;
    texp_frag[pos] = f2bf(__expf(x[q] - lse));
  }
}

// ---------------- delta_0 = start + emit[t=0], tagged t=0 ----------------
// abuf word layout (per parity): [group g][batch-in-group rb][col-pair c2]
__global__ void alpha0_kernel(const float* __restrict__ start, const float* __restrict__ emitg,
                              u64* __restrict__ abuf)
{
  int i = blockIdx.x * 256 + threadIdx.x;   // 0..8191 = g*2048 + rb*512 + c2
  int g = i >> 11, rem = i & 2047, rb = rem >> 9, c2 = rem & 511;
  int b = g * 4 + rb, j = c2 * 2;
  float v0 = start[j]     + emitg[b * 1024 + j];
  float v1 = start[j + 1] + emitg[b * 1024 + j + 1];
  u32 lo = (u32)f2bf(v0) | ((u32)f2bf(v1) << 16);
  abuf[i] = (u64)lo;   // tag 0
}

// ---------------- persistent forward scan: 4 independent groups of 16 blocks ----------------
// Group g owns batches [4g, 4g+4). Block pg (0..15) in a group owns cols [64pg, 64pg+64),
// wave w owns colblock cb = 4pg+w (16 cols). Exchange: tagged u64 {2x bf16 delta, tag}.
// MFMA A rows 0-3 = the 4 batches, rows 4-15 zeroed once. Split-N across waves: each
// wave's accumulator is complete -> no cross-wave sum, parallel epilogue/stores.
__global__ __launch_bounds__(256, 1) void scan_kernel(
    const ushort* __restrict__ texp_frag,
    const float* __restrict__ emitg,
    u64* __restrict__ abuf,             // [2 parity][4 group][2048]
    float* __restrict__ out)
{
  __shared__ ushort A[16 * 1032];       // A-tile: rows=batch (0-3 live), cols=1024 k
  __shared__ float redm[4][4];          // [wave][batch]
  int tid = threadIdx.x, lane = tid & 63, wave = tid >> 6;
  int r16 = lane & 15, quad = lane >> 4;
  int p = blockIdx.x, g = p & 3, pg = p >> 2;
  u64* gx = abuf + g * 2048;
  int cb = 4 * pg + wave;
  const short8* tf = (const short8*)texp_frag + (size_t)cb * 32 * 64;

  for (int idx = tid; idx < 8256; idx += 256) ((u32*)A)[idx] = 0;
  __syncthreads();

  float Bsum[4] = {0.f, 0.f, 0.f, 0.f};
  u64 d[8];

  for (int t = 1; t < 256; ++t) {
    // prefetch this step's emission (quad0 lanes consume in epilogue)
    float ep[4] = {0.f, 0.f, 0.f, 0.f};
    if (quad == 0) {
#pragma unroll
      for (int rr = 0; rr < 4; ++rr)
        ep[rr] = emitg[(size_t)(t * 16 + g * 4 + rr) * 1024 + cb * 16 + r16];
    }

    // ---- poll previous delta (8 coalesced tagged words per thread) ----
    {
      u32 want = (u32)(t - 1);
      const u64* buf = gx + ((t - 1) & 1) * 8192;
      u32 pend = 0xFFu; bool first = true;
      while (pend) {
        if (!first) __builtin_amdgcn_s_sleep(1);
        first = false;
        u64 x[8];
#pragma unroll
        for (int i = 0; i < 8; ++i)
          if (pend & (1u << i))
            x[i] = __hip_atomic_load(buf + i * 256 + tid,
                                     __ATOMIC_RELAXED, __HIP_MEMORY_SCOPE_AGENT);
#pragma unroll
        for (int i = 0; i < 8; ++i)
          if ((pend & (1u << i)) && (u32)(x[i] >> 32) == want) {
            d[i] = x[i]; pend &= ~(1u << i);
          }
      }
    }

    // ---- unpack + per-batch max (word i: batch = i>>1, c2 = (i&1)*256+tid) ----
    float v[8][2], ml[4];
#pragma unroll
    for (int i = 0; i < 8; ++i) {
      u32 lo = (u32)d[i];
      v[i][0] = bflo2f(lo); v[i][1] = bfhi2f(lo);
    }
#pragma unroll
    for (int b = 0; b < 4; ++b)
      ml[b] = fmaxf(fmaxf(v[2 * b][0], v[2 * b][1]), fmaxf(v[2 * b + 1][0], v[2 * b + 1][1]));
#pragma unroll
    for (int b = 0; b < 4; ++b)
      for (int m = 1; m < 64; m <<= 1) ml[b] = fmaxf(ml[b], __shfl_xor(ml[b], m));
    if (lane == 0) {
#pragma unroll
      for (int b = 0; b < 4; ++b) redm[wave][b] = ml[b];
    }
    __syncthreads();                       // sync1 (also fences prev step's A reads)
    float m4[4];
#pragma unroll
    for (int b = 0; b < 4; ++b) {
      m4[b] = fmaxf(fmaxf(redm[0][b], redm[1][b]), fmaxf(redm[2][b], redm[3][b]));
      Bsum[b] += m4[b];
    }
    // ---- exp + write A-tile rows 0-3 ----
#pragma unroll
    for (int i = 0; i < 8; ++i) {
      int b = i >> 1, c2 = (i & 1) * 256 + tid;
      u32 w = (u32)f2bf(__expf(v[i][0] - m4[b])) |
              ((u32)f2bf(__expf(v[i][1] - m4[b])) << 16);
      *(u32*)(A + b * 1032 + c2 * 2) = w;
    }
    __syncthreads();                       // sync2

    // ---- K-loop: wave computes its 16 cols over full K=1024 ----
    f32x4 acc = {0.f, 0.f, 0.f, 0.f};
#pragma unroll 8
    for (int k = 0; k < 32; ++k) {
      short8 a = *(const short8*)(A + r16 * 1032 + k * 32 + quad * 8);
      short8 b = tf[k * 64 + lane];
      acc = __builtin_amdgcn_mfma_f32_16x16x32_bf16(a, b, acc, 0, 0, 0);
    }

    // ---- epilogue: quad0 lanes hold batches 0-3 for col cb*16+r16 ----
    float dv[4], pv[4];
#pragma unroll
    for (int rr = 0; rr < 4; ++rr) dv[rr] = __logf(acc[rr]) + ep[rr];
#pragma unroll
    for (int rr = 0; rr < 4; ++rr) pv[rr] = __shfl_xor(dv[rr], 1);
    if (quad == 0 && (lane & 1) == 0) {
      u64* ob = gx + (t & 1) * 8192;
      int c2 = pg * 32 + wave * 8 + (r16 >> 1);
      u64 tag = ((u64)(u32)t) << 32;
#pragma unroll
      for (int rr = 0; rr < 4; ++rr) {
        u32 lo = (u32)f2bf(dv[rr]) | ((u32)f2bf(pv[rr]) << 16);
        __hip_atomic_store(ob + rr * 512 + c2, tag | (u64)lo,
                           __ATOMIC_RELAXED, __HIP_MEMORY_SCOPE_AGENT);
      }
    }
  }

  // ---- final: group leader reduces its 4 batches, atomicAdd into out ----
  if (pg == 0) {
    u32 want = 255;
    const u64* buf = gx + 8192;            // parity 1
    u32 pend = 0xFFu; bool first = true;
    while (pend) {
      if (!first) __builtin_amdgcn_s_sleep(1);
      first = false;
      u64 x[8];
#pragma unroll
      for (int i = 0; i < 8; ++i)
        if (pend & (1u << i))
          x[i] = __hip_atomic_load(buf + i * 256 + tid,
                                   __ATOMIC_RELAXED, __HIP_MEMORY_SCOPE_AGENT);
#pragma unroll
      for (int i = 0; i < 8; ++i)
        if ((pend & (1u << i)) && (u32)(x[i] >> 32) == want) {
          d[i] = x[i]; pend &= ~(1u << i);
        }
    }
    float v[8][2], ml[4];
#pragma unroll
    for (int i = 0; i < 8; ++i) {
      u32 lo = (u32)d[i];
      v[i][0] = bflo2f(lo); v[i][1] = bfhi2f(lo);
    }
#pragma unroll
    for (int b = 0; b < 4; ++b)
      ml[b] = fmaxf(fmaxf(v[2 * b][0], v[2 * b][1]), fmaxf(v[2 * b + 1][0], v[2 * b + 1][1]));
#pragma unroll
    for (int b = 0; b < 4; ++b)
      for (int m = 1; m < 64; m <<= 1) ml[b] = fmaxf(ml[b], __shfl_xor(ml[b], m));
    if (lane == 0) {
#pragma unroll
      for (int b = 0; b < 4; ++b) redm[wave][b] = ml[b];
    }
    __syncthreads();
    float m4[4];
#pragma unroll
    for (int b = 0; b < 4; ++b)
      m4[b] = fmaxf(fmaxf(redm[0][b], redm[1][b]), fmaxf(redm[2][b], redm[3][b]));
    __syncthreads();
    float sl[4];
#pragma unroll
    for (int b = 0; b < 4; ++b) {
      sl[b] = __expf(v[2 * b][0] - m4[b]) + __expf(v[2 * b][1] - m4[b]) +
              __expf(v[2 * b + 1][0] - m4[b]) + __expf(v[2 * b + 1][1] - m4[b]);
      for (int m = 1; m < 64; m <<= 1) sl[b] += __shfl_xor(sl[b], m);
    }
    if (lane == 0) {
#pragma unroll
      for (int b = 0; b < 4; ++b) redm[wave][b] = sl[b];
    }
    __syncthreads();
    if (tid == 0) {
      float partial = 0.f;
#pragma unroll
      for (int b = 0; b < 4; ++b)
        partial += Bsum[b] + m4[b] +
                   __logf(redm[0][b] + redm[1][b] + redm[2][b] + redm[3][b]);
      atomicAdd(out, partial);
    }
  }
}

extern "C" void kernel_launch(void* const* d_in, const int* in_sizes, int n_in,
                              void* d_out, int out_size, void* d_ws, size_t ws_size,
                              hipStream_t stream)
{
  (void)in_sizes; (void)n_in; (void)out_size; (void)ws_size;
  const float* start_emb = (const float*)d_in[0];
  const float* state_emb = (const float*)d_in[1];
  const float* pre_emb   = (const float*)d_in[2];
  const float* s_W1 = (const float*)d_in[3];  const float* s_b1 = (const float*)d_in[4];
  const float* s_W2 = (const float*)d_in[5];  const float* s_b2 = (const float*)d_in[6];
  const float* s_g  = (const float*)d_in[7];  const float* s_be = (const float*)d_in[8];
  const float* s_Wo = (const float*)d_in[9];  const float* s_bo = (const float*)d_in[10];
  const float* t_W1 = (const float*)d_in[11]; const float* t_b1 = (const float*)d_in[12];
  const float* t_W2 = (const float*)d_in[13]; const float* t_b2 = (const float*)d_in[14];
  const float* t_g  = (const float*)d_in[15]; const float* t_be = (const float*)d_in[16];
  const float* t_Wo = (const float*)d_in[17]; const float* t_bo = (const float*)d_in[18];
  const float* e_W1 = (const float*)d_in[19]; const float* e_b1 = (const float*)d_in[20];
  const float* e_W2 = (const float*)d_in[21]; const float* e_b2 = (const float*)d_in[22];
  const float* e_g  = (const float*)d_in[23]; const float* e_be = (const float*)d_in[24];
  const float* e_Wo = (const float*)d_in[25]; const float* e_bo = (const float*)d_in[26];
  const int*   text = (const int*)d_in[27];
  float* out = (float*)d_out;

  char* ws = (char*)d_ws;
  size_t off = 0;
  auto alloc = [&](size_t bytes) -> char* {
    char* p = ws + off;
    off = (off + bytes + 255) & ~(size_t)255;
    return p;
  };
  float* esum       = (float*)alloc(1024 * 4);             // @0 (memset below)
  u64* abuf         = (u64*)alloc(2 * 8192 * 8);           // tagged delta exchange
  float* start_v    = (float*)alloc(1024 * 4);
  float* h_s        = (float*)alloc(1024 * 256 * 4);
  float* h_t        = (float*)alloc(1024 * 256 * 4);
  float* h_e        = (float*)alloc(1024 * 256 * 4);
  ushort* h_t_bf    = (ushort*)alloc(1024 * 256 * 2);
  ushort* h_e_bf    = (ushort*)alloc(1024 * 256 * 2);
  ushort* tWo_bf    = (ushort*)alloc(1024 * 256 * 2);
  ushort* eWo_bf    = (ushort*)alloc(10000 * 256 * 2);
  float* tlogits    = (float*)alloc(1024 * 1024 * 4);
  ushort* texp_frag = (ushort*)alloc(1024 * 1024 * 2);
  float* emitg      = (float*)alloc(4096 * 1024 * 4);

  hipMemsetAsync(ws, 0, 4096, stream);       // esum
  hipMemsetAsync(d_out, 0, 4, stream);       // leaders atomicAdd into out

  cast_kernel<<<256, 256, 0, stream>>>(t_Wo, tWo_bf, 1024 * 256);
  cast_kernel<<<512, 256, 0, stream>>>(e_Wo, eWo_bf, 10000 * 256);

  mlp_kernel<<<64, 256, 0, stream>>>(start_emb, s_W1, s_b1, s_W2, s_b2, s_g, s_be, h_s, nullptr);
  mlp_kernel<<<64, 256, 0, stream>>>(state_emb, t_W1, t_b1, t_W2, t_b2, t_g, t_be, h_t, h_t_bf);
  mlp_kernel<<<64, 256, 0, stream>>>(pre_emb,  e_W1, e_b1, e_W2, e_b2, e_g, e_be, h_e, h_e_bf);

  shead_kernel<<<1, 1024, 0, stream>>>(h_s, s_Wo, s_bo, start_v);

  gemm_kernel<<<dim3(16, 32),  256, 0, stream>>>(h_t_bf, tWo_bf, 0, 1024,  t_bo, tlogits, nullptr, nullptr);
  trans_kernel<<<1024, 256, 0, stream>>>(tlogits, texp_frag);
  gemm_kernel<<<dim3(16, 313), 256, 0, stream>>>(h_e_bf, eWo_bf, 1, 10000, e_bo, nullptr, esum, nullptr);
  gemm_kernel<<<dim3(16, 128), 256, 0, stream>>>(h_e_bf, eWo_bf, 2, 4096,  e_bo, emitg, esum, text);

  alpha0_kernel<<<32, 256, 0, stream>>>(start_v, emitg, (u64*)abuf);
  scan_kernel<<<GBLK, 256, 0, stream>>>(texp_frag, emitg, abuf, out);
}

// Round 7
// 1328.150 us; speedup vs baseline: 2.0470x; 1.1470x over previous
//
#include <hip/hip_runtime.h>
#include <hip/hip_bf16.h>

typedef __attribute__((ext_vector_type(8))) short short8;
typedef __attribute__((ext_vector_type(4))) float f32x4;
typedef unsigned short ushort;
typedef unsigned long long u64;
typedef unsigned int u32;

#define GBLK 64   // 8 groups x 8 blocks; trivially co-resident on 256 CUs

__device__ inline ushort f2bf(float x) {
  __hip_bfloat16 h = __float2bfloat16(x);
  return *reinterpret_cast<ushort*>(&h);
}
__device__ inline float bfhi2f(u32 lo) {
  union { u32 u; float f; } c; c.u = lo & 0xFFFF0000u; return c.f;
}
__device__ inline float bflo2f(u32 lo) {
  union { u32 u; float f; } c; c.u = lo << 16; return c.f;
}

// ---------------- merged casts f32 -> bf16 ----------------
__global__ void cast2_kernel(const float* __restrict__ a, ushort* __restrict__ oa, int na,
                             const float* __restrict__ b, ushort* __restrict__ ob, int nb) {
  int i = blockIdx.x * blockDim.x + threadIdx.x;
  int st = gridDim.x * blockDim.x;
  for (; i < na + nb; i += st) {
    if (i < na) oa[i] = f2bf(a[i]);
    else        ob[i - na] = f2bf(b[i - na]);
  }
}

// ---------------- 3 residual MLPs in one dispatch (blockIdx.y selects) ----------------
__global__ __launch_bounds__(256) void mlp3_kernel(
    const float* X0, const float* W10, const float* b10, const float* W20, const float* b20,
    const float* g0, const float* be0, float* of0, ushort* ob0,
    const float* X1, const float* W11, const float* b11, const float* W21, const float* b21,
    const float* g1, const float* be1, float* of1, ushort* ob1,
    const float* X2, const float* W12, const float* b12, const float* W22, const float* b22,
    const float* g2, const float* be2, float* of2, ushort* ob2)
{
  const float *X, *W1, *b1, *W2, *b2, *g, *beta; float* of32; ushort* obf;
  int y = blockIdx.y;
  if (y == 0)      { X=X0; W1=W10; b1=b10; W2=W20; b2=b20; g=g0; beta=be0; of32=of0; obf=ob0; }
  else if (y == 1) { X=X1; W1=W11; b1=b11; W2=W21; b2=b21; g=g1; beta=be1; of32=of1; obf=ob1; }
  else             { X=X2; W1=W12; b1=b12; W2=W22; b2=b22; g=g2; beta=be2; of32=of2; obf=ob2; }

  __shared__ float Xs[16 * 260];
  __shared__ float H1s[16 * 260];
  __shared__ float mu_s[16], rs_s[16];
  int tid = threadIdx.x;
  int r0 = blockIdx.x * 16;
  for (int q = 0; q < 16; ++q) Xs[q * 260 + tid] = X[(r0 + q) * 256 + tid];
  __syncthreads();
  int r = tid & 15, jg = tid >> 4;
  for (int jj = 0; jj < 16; ++jj) {
    int j = jg * 16 + jj;
    const float4* wrow = (const float4*)(W1 + j * 256);
    const float4* xrow = (const float4*)(Xs + r * 260);
    float acc = 0.f;
#pragma unroll 8
    for (int kq = 0; kq < 64; ++kq) {
      float4 w = wrow[kq], x = xrow[kq];
      acc += w.x * x.x + w.y * x.y + w.z * x.z + w.w * x.w;
    }
    acc += b1[j];
    H1s[r * 260 + j] = acc > 0.f ? acc : 0.f;
  }
  __syncthreads();
  for (int jj = 0; jj < 16; ++jj) {
    int j = jg * 16 + jj;
    const float4* wrow = (const float4*)(W2 + j * 256);
    const float4* hrow = (const float4*)(H1s + r * 260);
    float acc = 0.f;
#pragma unroll 8
    for (int kq = 0; kq < 64; ++kq) {
      float4 w = wrow[kq], x = hrow[kq];
      acc += w.x * x.x + w.y * x.y + w.z * x.z + w.w * x.w;
    }
    acc += b2[j];
    float v = (acc > 0.f ? acc : 0.f) + H1s[r * 260 + j];
    Xs[r * 260 + j] = v;
  }
  __syncthreads();
  if (tid < 16) {
    float s = 0.f, s2 = 0.f;
    for (int k = 0; k < 256; ++k) { float x = Xs[tid * 260 + k]; s += x; s2 += x * x; }
    float mu = s * (1.0f / 256.0f);
    float var = s2 * (1.0f / 256.0f) - mu * mu;
    mu_s[tid] = mu; rs_s[tid] = rsqrtf(var + 1e-5f);
  }
  __syncthreads();
  for (int q = 0; q < 16; ++q) {
    float x = (Xs[q * 260 + tid] - mu_s[q]) * rs_s[q] * g[tid] + beta[tid];
    if (of32) of32[(r0 + q) * 256 + tid] = x;
    if (obf)  obf[(r0 + q) * 256 + tid] = f2bf(x);
  }
}

// ---------------- start head ----------------
__global__ __launch_bounds__(1024) void shead_kernel(
    const float* __restrict__ h, const float* __restrict__ Wo, const float* __restrict__ bo,
    float* __restrict__ start)
{
  __shared__ float red[16];
  __shared__ float lse_s;
  int tid = threadIdx.x;
  const float4* wr = (const float4*)Wo;
  const float4* hr = (const float4*)(h + tid * 256);
  float acc = 0.f;
  for (int kq = 0; kq < 64; ++kq) {
    float4 w = wr[kq], x = hr[kq];
    acc += w.x * x.x + w.y * x.y + w.z * x.z + w.w * x.w;
  }
  acc += bo[0];
  float s = __expf(acc);
  for (int m = 1; m < 64; m <<= 1) s += __shfl_xor(s, m);
  if ((tid & 63) == 0) red[tid >> 6] = s;
  __syncthreads();
  if (tid == 0) {
    float t = 0.f;
    for (int w = 0; w < 16; ++w) t += red[w];
    lse_s = logf(t);
  }
  __syncthreads();
  start[tid] = acc - lse_s;
}

// ---------------- bf16 MFMA GEMM, tile 64x32, K=256, D = A @ B^T ----------------
__global__ __launch_bounds__(256) void gemm_kernel(
    const ushort* __restrict__ A, const ushort* __restrict__ Bw,
    int mode, int Nvalid,
    const float* __restrict__ bias,
    float* __restrict__ out, float* __restrict__ esum, const int* __restrict__ text)
{
  __shared__ ushort As[64 * 264];
  __shared__ ushort Bs[32 * 264];
  int tid = threadIdx.x;
  int m0 = blockIdx.x * 64, n0 = blockIdx.y * 32;
#pragma unroll
  for (int q = 0; q < 8; ++q) {
    int idx = q * 256 + tid;
    int row = idx >> 5, c8 = idx & 31;
    *(short8*)(As + row * 264 + c8 * 8) = *(const short8*)(A + (m0 + row) * 256 + c8 * 8);
  }
#pragma unroll
  for (int q = 0; q < 4; ++q) {
    int idx = q * 256 + tid;
    int row = idx >> 5, c8 = idx & 31;
    int grow = n0 + row;
    short8 val = {0, 0, 0, 0, 0, 0, 0, 0};
    if (mode == 2) {
      int v = text[(grow & 15) * 256 + (grow >> 4)];
      val = *(const short8*)(Bw + v * 256 + c8 * 8);
    } else if (grow < Nvalid) {
      val = *(const short8*)(Bw + grow * 256 + c8 * 8);
    }
    *(short8*)(Bs + row * 264 + c8 * 8) = val;
  }
  __syncthreads();
  int lane = tid & 63, wave = tid >> 6;
  int r16 = lane & 15, quad = lane >> 4;
  f32x4 acc0 = {0.f, 0.f, 0.f, 0.f}, acc1 = {0.f, 0.f, 0.f, 0.f};
#pragma unroll
  for (int kb = 0; kb < 8; ++kb) {
    short8 a  = *(const short8*)(As + (wave * 16 + r16) * 264 + kb * 32 + quad * 8);
    short8 b0 = *(const short8*)(Bs + r16 * 264 + kb * 32 + quad * 8);
    short8 b1 = *(const short8*)(Bs + (16 + r16) * 264 + kb * 32 + quad * 8);
    acc0 = __builtin_amdgcn_mfma_f32_16x16x32_bf16(a, b0, acc0, 0, 0, 0);
    acc1 = __builtin_amdgcn_mfma_f32_16x16x32_bf16(a, b1, acc1, 0, 0, 0);
  }
  if (mode == 0) {
#pragma unroll
    for (int rr = 0; rr < 4; ++rr) {
      int row = m0 + wave * 16 + quad * 4 + rr;
      int c0 = n0 + r16, c1 = n0 + 16 + r16;
      out[row * 1024 + c0] = acc0[rr] + bias[c0];
      out[row * 1024 + c1] = acc1[rr] + bias[c1];
    }
  } else if (mode == 1) {
    float sums[4];
#pragma unroll
    for (int rr = 0; rr < 4; ++rr) {
      int c0 = n0 + r16, c1 = n0 + 16 + r16;
      float p0 = (c0 < Nvalid) ? __expf(acc0[rr] + bias[c0]) : 0.f;
      float p1 = (c1 < Nvalid) ? __expf(acc1[rr] + bias[c1]) : 0.f;
      float s = p0 + p1;
      s += __shfl_xor(s, 1); s += __shfl_xor(s, 2);
      s += __shfl_xor(s, 4); s += __shfl_xor(s, 8);
      sums[rr] = s;
    }
    if (r16 == 0) {
#pragma unroll
      for (int rr = 0; rr < 4; ++rr)
        atomicAdd(esum + m0 + wave * 16 + quad * 4 + rr, sums[rr]);
    }
  } else {
    int c0 = m0 + wave * 16 + quad * 4;
    int tb0 = n0 + r16, tb1 = n0 + 16 + r16;
    int v0 = text[(tb0 & 15) * 256 + (tb0 >> 4)];
    int v1 = text[(tb1 & 15) * 256 + (tb1 >> 4)];
    float l0 = logf(esum[c0]), l1 = logf(esum[c0 + 1]);
    float l2 = logf(esum[c0 + 2]), l3 = logf(esum[c0 + 3]);
    float4 o0, o1;
    o0.x = acc0[0] + bias[v0] - l0; o0.y = acc0[1] + bias[v0] - l1;
    o0.z = acc0[2] + bias[v0] - l2; o0.w = acc0[3] + bias[v0] - l3;
    o1.x = acc1[0] + bias[v1] - l0; o1.y = acc1[1] + bias[v1] - l1;
    o1.z = acc1[2] + bias[v1] - l2; o1.w = acc1[3] + bias[v1] - l3;
    *(float4*)(out + tb0 * 1024 + c0) = o0;
    *(float4*)(out + tb1 * 1024 + c0) = o1;
  }
}

// ---------------- transition: per-row log_softmax, scatter exp(T) in B-fragment order ----------------
__global__ __launch_bounds__(256) void trans_kernel(
    const float* __restrict__ logits, ushort* __restrict__ texp_frag)
{
  __shared__ float red[4];
  __shared__ float lse_s;
  int i = blockIdx.x, tid = threadIdx.x;
  float x[4];
  float s = 0.f;
#pragma unroll
  for (int q = 0; q < 4; ++q) { x[q] = logits[i * 1024 + q * 256 + tid]; s += __expf(x[q]); }
  for (int m = 1; m < 64; m <<= 1) s += __shfl_xor(s, m);
  if ((tid & 63) == 0) red[tid >> 6] = s;
  __syncthreads();
  if (tid == 0) lse_s = logf(red[0] + red[1] + red[2] + red[3]);
  __syncthreads();
  float lse = lse_s;
  int kblk = i >> 5, quad = (i >> 3) & 3, idx = i & 7;
#pragma unroll
  for (int q = 0; q < 4; ++q) {
    int j = q * 256 + tid;
    int pos = (((j >> 4) * 32 + kblk) * 64 + quad * 16 + (j & 15)) * 8 + idx;
    texp_frag[pos] = f2bf(__expf(x[q] - lse));
  }
}

// ---------------- persistent forward scan: 8 groups x 8 blocks ----------------
// Group g = p&7 owns batches {2g, 2g+1}; block pg = p>>3 owns cols [128pg, 128pg+128);
// wave w owns 2 col-tiles at n0 = 128pg + 32w. Exchange: tagged u64
// {tag32 | 2x bf16 delta} via HIP relaxed agent-scope atomics (R4-proven).
// Normalizer = delta[col 0] broadcast word. Split-N waves -> no cross-wave reduce.
__global__ __launch_bounds__(256, 1) void scan_kernel(
    const ushort* __restrict__ texp_frag,
    const float* __restrict__ emitg,
    const float* __restrict__ start_v,
    u64* __restrict__ abuf,            // [8 group][2 parity][2 rb][512]
    float* __restrict__ out)
{
  __shared__ ushort Atile[2 * 1024];   // rows = 2 batches, 1024 cols bf16
  __shared__ ushort zeros16[32];
  __shared__ float  redw[4][2];
  int tid = threadIdx.x, lane = tid & 63, wave = tid >> 6;
  int r16 = lane & 15, quad = lane >> 4;
  int p = blockIdx.x, g = p & 7, pg = p >> 3;
  u64* gx = abuf + g * 2048;
  int b0 = 2 * g, b1 = 2 * g + 1;
  int n0 = pg * 128 + wave * 32;       // wave's first col (2 tiles: n0, n0+16)
  const short8* tf0 = (const short8*)texp_frag + (size_t)(pg * 8 + wave * 2) * 2048;
  const short8* tf1 = tf0 + 2048;

  if (tid < 32) zeros16[tid] = 0;
  __syncthreads();

  float Bsum0 = 0.f, Bsum1 = 0.f;

  for (int t = 1; t < 256; ++t) {
    // emission prefetch for this step's epilogue (quad0 lanes consume)
    float e00 = 0.f, e01 = 0.f, e10 = 0.f, e11 = 0.f;
    if (quad == 0) {
      e00 = emitg[(size_t)(t * 16 + b0) * 1024 + n0 + r16];
      e10 = emitg[(size_t)(t * 16 + b1) * 1024 + n0 + r16];
      e01 = emitg[(size_t)(t * 16 + b0) * 1024 + n0 + 16 + r16];
      e11 = emitg[(size_t)(t * 16 + b1) * 1024 + n0 + 16 + r16];
    }

    float va[4][2];   // word i: rb = i>>1, c2 = (i&1)*256 + tid -> cols 2c2, 2c2+1
    float mA, mB;
    if (t == 1) {
      // delta0 computed locally (identical in all blocks): start + emit[t=0]
      mA = start_v[0] + emitg[(size_t)b0 * 1024];
      mB = start_v[0] + emitg[(size_t)b1 * 1024];
#pragma unroll
      for (int i = 0; i < 4; ++i) {
        int rb = i >> 1, c2 = (i & 1) * 256 + tid;
        const float* eb = emitg + (size_t)(rb ? b1 : b0) * 1024;
        va[i][0] = start_v[2 * c2]     + eb[2 * c2];
        va[i][1] = start_v[2 * c2 + 1] + eb[2 * c2 + 1];
      }
    } else {
      u32 want = (u32)(t - 1);
      const u64* buf = gx + ((t - 1) & 1) * 1024;
      u64 d[4], nw0 = 0, nw1 = 0;
      u32 pend = 0x3Fu; bool first = true;
      while (pend) {
        if (!first) __builtin_amdgcn_s_sleep(1);
        first = false;
        u64 x[6];
        if (pend & 1u)  x[0] = __hip_atomic_load(buf + tid,       __ATOMIC_RELAXED, __HIP_MEMORY_SCOPE_AGENT);
        if (pend & 2u)  x[1] = __hip_atomic_load(buf + 256 + tid, __ATOMIC_RELAXED, __HIP_MEMORY_SCOPE_AGENT);
        if (pend & 4u)  x[2] = __hip_atomic_load(buf + 512 + tid, __ATOMIC_RELAXED, __HIP_MEMORY_SCOPE_AGENT);
        if (pend & 8u)  x[3] = __hip_atomic_load(buf + 768 + tid, __ATOMIC_RELAXED, __HIP_MEMORY_SCOPE_AGENT);
        if (pend & 16u) x[4] = __hip_atomic_load(buf,             __ATOMIC_RELAXED, __HIP_MEMORY_SCOPE_AGENT);
        if (pend & 32u) x[5] = __hip_atomic_load(buf + 512,       __ATOMIC_RELAXED, __HIP_MEMORY_SCOPE_AGENT);
#pragma unroll
        for (int i = 0; i < 4; ++i)
          if ((pend & (1u << i)) && (u32)(x[i] >> 32) == want) { d[i] = x[i]; pend &= ~(1u << i); }
        if ((pend & 16u) && (u32)(x[4] >> 32) == want) { nw0 = x[4]; pend &= ~16u; }
        if ((pend & 32u) && (u32)(x[5] >> 32) == want) { nw1 = x[5]; pend &= ~32u; }
      }
      mA = bflo2f((u32)nw0); mB = bflo2f((u32)nw1);
#pragma unroll
      for (int i = 0; i < 4; ++i) {
        u32 lo = (u32)d[i];
        va[i][0] = bflo2f(lo); va[i][1] = bfhi2f(lo);
      }
    }
    Bsum0 += mA; Bsum1 += mB;

    __syncthreads();   // all waves done reading Atile of previous step
    // exp + pack into Atile rows 0/1
#pragma unroll
    for (int i = 0; i < 4; ++i) {
      int rb = i >> 1, c2 = (i & 1) * 256 + tid;
      float m = rb ? mB : mA;
      u32 w = (u32)f2bf(__expf(va[i][0] - m)) |
              ((u32)f2bf(__expf(va[i][1] - m)) << 16);
      *(u32*)(Atile + rb * 1024 + c2 * 2) = w;
    }
    __syncthreads();   // Atile ready

    // K-loop: wave computes its 2 col-tiles over full K=1024
    f32x4 acc0 = {0.f, 0.f, 0.f, 0.f}, acc1 = {0.f, 0.f, 0.f, 0.f};
#pragma unroll 8
    for (int k = 0; k < 32; ++k) {
      const ushort* ap = (r16 < 2) ? (Atile + r16 * 1024 + k * 32 + quad * 8)
                                   : (zeros16 + quad * 8);
      short8 a = *(const short8*)ap;
      acc0 = __builtin_amdgcn_mfma_f32_16x16x32_bf16(a, tf0[k * 64 + lane], acc0, 0, 0, 0);
      acc1 = __builtin_amdgcn_mfma_f32_16x16x32_bf16(a, tf1[k * 64 + lane], acc1, 0, 0, 0);
    }

    // epilogue: quad0 lanes hold batch0 (reg0) and batch1 (reg1) for col n0(+16)+r16
    float d00 = __logf(acc0[0]) + e00, d10 = __logf(acc0[1]) + e10;
    float d01 = __logf(acc1[0]) + e01, d11 = __logf(acc1[1]) + e11;
    float p00 = __shfl_xor(d00, 1), p10 = __shfl_xor(d10, 1);
    float p01 = __shfl_xor(d01, 1), p11 = __shfl_xor(d11, 1);
    if (quad == 0 && !(r16 & 1)) {
      u64 tag = ((u64)(u32)t) << 32;
      u64* ob = gx + (t & 1) * 1024;
      int c2a = (n0 + r16) >> 1;
      int c2b = (n0 + 16 + r16) >> 1;
      __hip_atomic_store(ob + c2a,       tag | (u64)((u32)f2bf(d00) | ((u32)f2bf(p00) << 16)),
                         __ATOMIC_RELAXED, __HIP_MEMORY_SCOPE_AGENT);
      __hip_atomic_store(ob + c2b,       tag | (u64)((u32)f2bf(d01) | ((u32)f2bf(p01) << 16)),
                         __ATOMIC_RELAXED, __HIP_MEMORY_SCOPE_AGENT);
      __hip_atomic_store(ob + 512 + c2a, tag | (u64)((u32)f2bf(d10) | ((u32)f2bf(p10) << 16)),
                         __ATOMIC_RELAXED, __HIP_MEMORY_SCOPE_AGENT);
      __hip_atomic_store(ob + 512 + c2b, tag | (u64)((u32)f2bf(d11) | ((u32)f2bf(p11) << 16)),
                         __ATOMIC_RELAXED, __HIP_MEMORY_SCOPE_AGENT);
    }
  }

  // ---- group leader (pg==0): reduce final delta + Bsum -> atomicAdd(out) ----
  if (pg == 0) {
    const u64* buf = gx + 1024;   // parity of t=255
    u64 d[4];
    u32 pend = 0xFu; bool first = true;
    while (pend) {
      if (!first) __builtin_amdgcn_s_sleep(1);
      first = false;
      u64 x[4];
      if (pend & 1u) x[0] = __hip_atomic_load(buf + tid,       __ATOMIC_RELAXED, __HIP_MEMORY_SCOPE_AGENT);
      if (pend & 2u) x[1] = __hip_atomic_load(buf + 256 + tid, __ATOMIC_RELAXED, __HIP_MEMORY_SCOPE_AGENT);
      if (pend & 4u) x[2] = __hip_atomic_load(buf + 512 + tid, __ATOMIC_RELAXED, __HIP_MEMORY_SCOPE_AGENT);
      if (pend & 8u) x[3] = __hip_atomic_load(buf + 768 + tid, __ATOMIC_RELAXED, __HIP_MEMORY_SCOPE_AGENT);
#pragma unroll
      for (int i = 0; i < 4; ++i)
        if ((pend & (1u << i)) && (u32)(x[i] >> 32) == 255u) { d[i] = x[i]; pend &= ~(1u << i); }
    }
    float lv[4][2];
#pragma unroll
    for (int i = 0; i < 4; ++i) {
      u32 lo = (u32)d[i];
      lv[i][0] = bflo2f(lo); lv[i][1] = bfhi2f(lo);
    }
    float M0 = fmaxf(fmaxf(lv[0][0], lv[0][1]), fmaxf(lv[1][0], lv[1][1]));
    float M1 = fmaxf(fmaxf(lv[2][0], lv[2][1]), fmaxf(lv[3][0], lv[3][1]));
    for (int m = 1; m < 64; m <<= 1) {
      M0 = fmaxf(M0, __shfl_xor(M0, m));
      M1 = fmaxf(M1, __shfl_xor(M1, m));
    }
    if (lane == 0) { redw[wave][0] = M0; redw[wave][1] = M1; }
    __syncthreads();
    M0 = fmaxf(fmaxf(redw[0][0], redw[1][0]), fmaxf(redw[2][0], redw[3][0]));
    M1 = fmaxf(fmaxf(redw[0][1], redw[1][1]), fmaxf(redw[2][1], redw[3][1]));
    __syncthreads();
    float S0 = __expf(lv[0][0] - M0) + __expf(lv[0][1] - M0) +
               __expf(lv[1][0] - M0) + __expf(lv[1][1] - M0);
    float S1 = __expf(lv[2][0] - M1) + __expf(lv[2][1] - M1) +
               __expf(lv[3][0] - M1) + __expf(lv[3][1] - M1);
    for (int m = 1; m < 64; m <<= 1) {
      S0 += __shfl_xor(S0, m);
      S1 += __shfl_xor(S1, m);
    }
    if (lane == 0) { redw[wave][0] = S0; redw[wave][1] = S1; }
    __syncthreads();
    if (tid == 0) {
      float s0 = redw[0][0] + redw[1][0] + redw[2][0] + redw[3][0];
      float s1 = redw[0][1] + redw[1][1] + redw[2][1] + redw[3][1];
      float total = (Bsum0 + M0 + __logf(s0)) + (Bsum1 + M1 + __logf(s1));
      atomicAdd(out, total);
    }
  }
}

extern "C" void kernel_launch(void* const* d_in, const int* in_sizes, int n_in,
                              void* d_out, int out_size, void* d_ws, size_t ws_size,
                              hipStream_t stream)
{
  (void)in_sizes; (void)n_in; (void)out_size; (void)ws_size;
  const float* start_emb = (const float*)d_in[0];
  const float* state_emb = (const float*)d_in[1];
  const float* pre_emb   = (const float*)d_in[2];
  const float* s_W1 = (const float*)d_in[3];  const float* s_b1 = (const float*)d_in[4];
  const float* s_W2 = (const float*)d_in[5];  const float* s_b2 = (const float*)d_in[6];
  const float* s_g  = (const float*)d_in[7];  const float* s_be = (const float*)d_in[8];
  const float* s_Wo = (const float*)d_in[9];  const float* s_bo = (const float*)d_in[10];
  const float* t_W1 = (const float*)d_in[11]; const float* t_b1 = (const float*)d_in[12];
  const float* t_W2 = (const float*)d_in[13]; const float* t_b2 = (const float*)d_in[14];
  const float* t_g  = (const float*)d_in[15]; const float* t_be = (const float*)d_in[16];
  const float* t_Wo = (const float*)d_in[17]; const float* t_bo = (const float*)d_in[18];
  const float* e_W1 = (const float*)d_in[19]; const float* e_b1 = (const float*)d_in[20];
  const float* e_W2 = (const float*)d_in[21]; const float* e_b2 = (const float*)d_in[22];
  const float* e_g  = (const float*)d_in[23]; const float* e_be = (const float*)d_in[24];
  const float* e_Wo = (const float*)d_in[25]; const float* e_bo = (const float*)d_in[26];
  const int*   text = (const int*)d_in[27];
  float* out = (float*)d_out;

  char* ws = (char*)d_ws;
  size_t off = 0;
  auto alloc = [&](size_t bytes) -> char* {
    char* p = ws + off;
    off = (off + bytes + 255) & ~(size_t)255;
    return p;
  };
  float* esum       = (float*)alloc(1024 * 4);     // @0 (memset)
  u64*   abuf       = (u64*)alloc(8 * 2048 * 8);   // 128KB tagged exchange
  float* start_v    = (float*)alloc(1024 * 4);
  float* h_s        = (float*)alloc(1024 * 256 * 4);
  ushort* h_t_bf    = (ushort*)alloc(1024 * 256 * 2);
  ushort* h_e_bf    = (ushort*)alloc(1024 * 256 * 2);
  ushort* tWo_bf    = (ushort*)alloc(1024 * 256 * 2);
  ushort* eWo_bf    = (ushort*)alloc(10000 * 256 * 2);
  float* tlogits    = (float*)alloc(1024 * 1024 * 4);
  ushort* texp_frag = (ushort*)alloc(1024 * 1024 * 2);
  float* emitg      = (float*)alloc(4096 * 1024 * 4);

  hipMemsetAsync(ws, 0, 4096, stream);   // esum
  hipMemsetAsync(d_out, 0, 4, stream);   // leaders atomicAdd into out

  cast2_kernel<<<768, 256, 0, stream>>>(t_Wo, tWo_bf, 1024 * 256, e_Wo, eWo_bf, 10000 * 256);

  mlp3_kernel<<<dim3(64, 3), 256, 0, stream>>>(
      start_emb, s_W1, s_b1, s_W2, s_b2, s_g, s_be, h_s, nullptr,
      state_emb, t_W1, t_b1, t_W2, t_b2, t_g, t_be, nullptr, h_t_bf,
      pre_emb,  e_W1, e_b1, e_W2, e_b2, e_g, e_be, nullptr, h_e_bf);

  shead_kernel<<<1, 1024, 0, stream>>>(h_s, s_Wo, s_bo, start_v);

  gemm_kernel<<<dim3(16, 32),  256, 0, stream>>>(h_t_bf, tWo_bf, 0, 1024,  t_bo, tlogits, nullptr, nullptr);
  trans_kernel<<<1024, 256, 0, stream>>>(tlogits, texp_frag);
  gemm_kernel<<<dim3(16, 313), 256, 0, stream>>>(h_e_bf, eWo_bf, 1, 10000, e_bo, nullptr, esum, nullptr);
  gemm_kernel<<<dim3(16, 128), 256, 0, stream>>>(h_e_bf, eWo_bf, 2, 4096,  e_bo, emitg, esum, text);

  scan_kernel<<<GBLK, 256, 0, stream>>>(texp_frag, emitg, start_v, abuf, out);
}